// Round 5
// baseline (338.622 us; speedup 1.0000x reference)
//
#include <hip/hip_runtime.h>
#include <hip/hip_bf16.h>
#include <math.h>

#define BATCH 8
#define SEQ   1024
#define DM    768
#define NHEAD 12
#define KVH   4
#define HD    64
#define REP   3

// softmax scale folded into Q weights, exp2 domain: 0.125 * log2(e)
#define QSCALE 0.18033688011112042f

typedef unsigned short u16;
typedef __attribute__((ext_vector_type(8))) __bf16 bf16x8;
typedef __attribute__((ext_vector_type(4))) float f32x4;
typedef __attribute__((ext_vector_type(4))) unsigned int u32x4;
typedef __attribute__((address_space(1))) const unsigned int gu32_c;
typedef __attribute__((address_space(3))) unsigned int su32;

// RTNE fp32 -> bf16 (finite values)
__device__ __forceinline__ u16 f2bf(float f) {
    unsigned int u = __float_as_uint(f);
    u += 0x7fffu + ((u >> 16) & 1u);
    return (u16)(u >> 16);
}

// ======== convert x -> bf16, vectorized (float4 in, ushort4 out) ============
__global__ __launch_bounds__(256) void cvt_x_k(
    const float* __restrict__ in, u16* __restrict__ o, int n4)
{
    const int i = blockIdx.x * 256 + threadIdx.x;
    if (i >= n4) return;
    const float4 v = ((const float4*)in)[i];
    ushort4 r;
    r.x = f2bf(v.x); r.y = f2bf(v.y); r.z = f2bf(v.z); r.w = f2bf(v.w);
    ((ushort4*)o)[i] = r;
}

// ==== build Wt[n][k] bf16 = concat(qw|kw|vw)[k][n] transposed+converted =====
// Q columns pre-scaled by QSCALE (softmax scale folded, exp2 domain).
__global__ __launch_bounds__(256) void cvt_wqkv_k(
    const float* __restrict__ qw, const float* __restrict__ kw,
    const float* __restrict__ vw, u16* __restrict__ wt)
{
    const int idx = blockIdx.x * 256 + threadIdx.x;   // idx = n*768 + k
    if (idx >= 1280 * DM) return;
    const int k = idx % DM;
    const int n = idx / DM;
    float v;
    if (n < 768)       v = qw[(size_t)k * 768 + n] * QSCALE;
    else if (n < 1024) v = kw[(size_t)k * 256 + (n - 768)];
    else               v = vw[(size_t)k * 256 + (n - 1024)];
    wt[idx] = f2bf(v);
}

__global__ __launch_bounds__(256) void cvt_wo_k(
    const float* __restrict__ ow, u16* __restrict__ wt)
{
    const int idx = blockIdx.x * 256 + threadIdx.x;   // idx = n*768 + k
    if (idx >= DM * DM) return;
    const int k = idx % DM;
    const int n = idx / DM;
    wt[idx] = f2bf(ow[(size_t)k * DM + n]);
}

// ======== 128x128-tile bf16 MFMA GEMM body (global_load_lds staging) ========
// [128][32] LDS tiles; wave ds_read_b128 span is contiguous 1024B -> conflict-
// free (m136 stride-1 case).  Do NOT widen to BK=64 without swizzle: [128][64]
// puts all 16 lo-lanes in the same 4 banks (16-way).
__device__ __forceinline__ void gemm128_body(
    const u16* __restrict__ A, const u16* __restrict__ B,
    int m0, int n0, u16* As, u16* Bs, f32x4 acc[4][4])
{
    const int tid  = threadIdx.x;
    const int lane = tid & 63;
    const int wid  = tid >> 6;
    const int wr = wid >> 1, wc = wid & 1;
    const int lo = lane & 15, hi = lane >> 4;

    const f32x4 z = {0.f, 0.f, 0.f, 0.f};
    #pragma unroll
    for (int i = 0; i < 4; i++)
        #pragma unroll
        for (int j = 0; j < 4; j++)
            acc[i][j] = z;

    for (int kt = 0; kt < DM; kt += 32) {
        #pragma unroll
        for (int r = 0; r < 2; ++r) {
            const int idx  = r * 256 + tid;           // chunk id, 512 per tile
            const int row  = idx >> 2;
            const int col  = (idx & 3) << 3;
            const int base = (r * 256 + wid * 64) * 8; // wave-uniform LDS elems
            __builtin_amdgcn_global_load_lds(
                (gu32_c*)&A[(size_t)(m0 + row) * DM + kt + col],
                (su32*)&As[base], 16, 0, 0);
            __builtin_amdgcn_global_load_lds(
                (gu32_c*)&B[(size_t)(n0 + row) * DM + kt + col],
                (su32*)&Bs[base], 16, 0, 0);
        }
        __syncthreads();
        bf16x8 af[4], bfr[4];
        #pragma unroll
        for (int i = 0; i < 4; i++) af[i]  = *(const bf16x8*)&As[(wr * 64 + i * 16 + lo) * 32 + hi * 8];
        #pragma unroll
        for (int j = 0; j < 4; j++) bfr[j] = *(const bf16x8*)&Bs[(wc * 64 + j * 16 + lo) * 32 + hi * 8];
        #pragma unroll
        for (int i = 0; i < 4; i++)
            #pragma unroll
            for (int j = 0; j < 4; j++)
                acc[i][j] = __builtin_amdgcn_mfma_f32_16x16x32_bf16(af[i], bfr[j], acc[i][j], 0, 0, 0);
        __syncthreads();
    }
}

// ======== QKV projection -> Q/K head-major [b,h,t,d]; V TRANSPOSED [b,g,d,t]
__global__ __launch_bounds__(256) void gemm_qkv(
    const u16* __restrict__ xb, const u16* __restrict__ wt,
    const float* __restrict__ qb, const float* __restrict__ kb,
    const float* __restrict__ vb,
    u16* __restrict__ Q, u16* __restrict__ K, u16* __restrict__ Vt)
{
    __shared__ __align__(16) u16 As[128 * 32];
    __shared__ __align__(16) u16 Bs[128 * 32];
    // XCD-chunked swizzle (640 % 8 == 0), id m-major so each XCD reuses x-panels
    const int id = (blockIdx.x & 7) * 80 + (blockIdx.x >> 3);
    const int m0 = (id / 10) * 128;
    const int n0 = (id % 10) * 128;
    f32x4 acc[4][4];
    gemm128_body(xb, wt, m0, n0, As, Bs, acc);

    const int tid = threadIdx.x;
    const int lane = tid & 63, wid = tid >> 6;
    const int wr = wid >> 1, wc = wid & 1;
    const int lo = lane & 15, hi = lane >> 4;

    #pragma unroll
    for (int j = 0; j < 4; j++) {
        const int n = n0 + wc * 64 + j * 16 + lo;
        if (n < 1024) {       // Q or K: [b,h,t,d] layout, scalar stores
            u16* outp; int nl, Hcnt; float bias;
            if (n < 768) { outp = Q; nl = n;       Hcnt = NHEAD; bias = qb[n] * QSCALE; }
            else         { outp = K; nl = n - 768; Hcnt = KVH;   bias = kb[nl]; }
            const int head = nl >> 6, d = nl & 63;
            #pragma unroll
            for (int i = 0; i < 4; i++) {
                #pragma unroll
                for (int r = 0; r < 4; r++) {
                    const int m = m0 + wr * 64 + i * 16 + hi * 4 + r;
                    const int b = m >> 10, t = m & 1023;
                    outp[(((size_t)(b * Hcnt + head)) * SEQ + t) * HD + d] =
                        f2bf(acc[i][j][r] + bias);
                }
            }
        } else {              // V: [b,g,d,t] layout, ushort4 stores (4 consecutive t)
            const int nl = n - 1024;
            const float bias = vb[nl];
            const int head = nl >> 6, d = nl & 63;
            #pragma unroll
            for (int i = 0; i < 4; i++) {
                ushort4 vs;
                vs.x = f2bf(acc[i][j][0] + bias);
                vs.y = f2bf(acc[i][j][1] + bias);
                vs.z = f2bf(acc[i][j][2] + bias);
                vs.w = f2bf(acc[i][j][3] + bias);
                const int m = m0 + wr * 64 + i * 16 + hi * 4;
                const int b = m >> 10, t = m & 1023;
                *(ushort4*)&Vt[(((size_t)(b * KVH + head)) * HD + d) * SEQ + t] = vs;
            }
        }
    }
}

// ======== output projection: attn[8192][768] bf16 @ Wo^T + ob -> fp32 =======
__global__ __launch_bounds__(256) void gemm_oproj(
    const u16* __restrict__ Ab, const u16* __restrict__ wt,
    const float* __restrict__ ob, float* __restrict__ outp)
{
    __shared__ __align__(16) u16 As[128 * 32];
    __shared__ __align__(16) u16 Bs[128 * 32];
    const int id = (blockIdx.x & 7) * 48 + (blockIdx.x >> 3);   // 384 % 8 == 0
    const int m0 = (id / 6) * 128;
    const int n0 = (id % 6) * 128;
    f32x4 acc[4][4];
    gemm128_body(Ab, wt, m0, n0, As, Bs, acc);

    const int tid = threadIdx.x;
    const int lane = tid & 63, wid = tid >> 6;
    const int wr = wid >> 1, wc = wid & 1;
    const int lo = lane & 15, hi = lane >> 4;

    #pragma unroll
    for (int j = 0; j < 4; j++) {
        const int n = n0 + wc * 64 + j * 16 + lo;
        const float bias = ob[n];
        #pragma unroll
        for (int i = 0; i < 4; i++) {
            #pragma unroll
            for (int r = 0; r < 4; r++) {
                const int m = m0 + wr * 64 + i * 16 + hi * 4 + r;
                outp[(size_t)m * DM + n] = acc[i][j][r] + bias;
            }
        }
    }
}

// ======== RoPE, Q and K fused in one launch (file-faithful interleave) ======
__global__ __launch_bounds__(256) void rope_naive(
    const __hip_bfloat16* __restrict__ Qin, __hip_bfloat16* __restrict__ Qout,
    const __hip_bfloat16* __restrict__ Kin, __hip_bfloat16* __restrict__ Kout,
    const int* __restrict__ pos)
{
    const long long qrows = (long long)BATCH * NHEAD * SEQ;   // 98304
    const long long krows = (long long)BATCH * KVH * SEQ;     // 32768
    const long long gid = (long long)blockIdx.x * 256 + threadIdx.x;
    if (gid >= (qrows + krows) * 64) return;
    long long row = gid >> 6;
    const int j = (int)(gid & 63);
    const __hip_bfloat16* in; __hip_bfloat16* outb;
    if (row < qrows) { in = Qin; outb = Qout; }
    else             { in = Kin; outb = Kout; row -= qrows; }
    const int t = (int)(row & (SEQ - 1));

    float p;
    if (pos[1] == 1)                              p = (float)pos[t];
    else if (((const float*)pos)[1] == 1.0f)      p = ((const float*)pos)[t];
    else                                          p = (float)pos[2 * t];

    const float inv = exp2f(-(float)(j & 31) * (13.287712379549449f / 32.0f));
    float sv, cv;
    sincosf(p * inv, &sv, &cv);
    const int partner = (j & 1) * 32 + (j >> 1) + ((j < 32) ? 16 : -16);
    const float sign  = (j < 32) ? -1.0f : 1.0f;
    const float val  = __bfloat162float(in[row * HD + j]);
    const float pv   = __bfloat162float(in[row * HD + partner]);
    outb[row * HD + j] = __float2bfloat16(val * cv + sign * pv * sv);
}

// ======== flash attention v5: one 16-row strip per wave ======================
// Grid 96 (b,h) x 16 = 1536 blocks, 4 waves.  Wave strip a = c + 16*wid in
// [0,64): rows [16a,16a+16).  6144 waves -> 6 waves/SIMD (vs 3 in v3): the
// per-tile serial chain (QK MFMA -> softmax -> PV MFMA) now overlaps across
// waves.  Scores in log2 domain (QSCALE folded into Q).  Per-lane partial l
// and per-lane defer-max check: no cross-lane ops in the common path (row
// reduces deferred to epilogue).  Scalar f2bf pack (NO inline-asm cvt_pk --
// m240: asm cvt_pk -37%).  K prefetch one tile ahead; setprio around MFMA.
__global__ __launch_bounds__(256, 4) void attn_mfma(
    const u16* __restrict__ Q, const u16* __restrict__ K,
    const u16* __restrict__ Vt, u16* __restrict__ outp)
{
    const int wg = (blockIdx.x & 7) * 192 + (blockIdx.x >> 3);  // XCD swizzle
    const int bh = wg >> 4;
    const int c  = wg & 15;
    const int b  = bh / NHEAD, h = bh % NHEAD;
    const int g  = h / REP;
    const int wid  = threadIdx.x >> 6;
    const int lane = threadIdx.x & 63;
    const int lo = lane & 15, hi = lane >> 4;

    const int a    = c + (wid << 4);         // strip 0..63 (16 q-rows)
    const int q0   = a << 4;
    const int nst  = (a >> 1) + 1;           // 32-row s-tiles
    const int dT   = a >> 1;                 // diagonal tile index
    const int msk0 = lo + ((a & 1) << 4);

    const u16* Qp = Q  + ((size_t)(b * NHEAD + h) * SEQ + q0) * HD;
    const u16* Kp = K  + (size_t)(b * KVH + g) * SEQ * HD;
    const u16* Vp = Vt + (size_t)(b * KVH + g) * SEQ * HD;   // [d][s]

    const bf16x8 qf0 = *(const bf16x8*)&Qp[(size_t)lo * HD + hi * 8];
    const bf16x8 qf1 = *(const bf16x8*)&Qp[(size_t)lo * HD + 32 + hi * 8];

    const f32x4 z = {0.f, 0.f, 0.f, 0.f};
    f32x4 O[4];
    #pragma unroll
    for (int dj = 0; dj < 4; ++dj) O[dj] = z;
    float m = -3.0e38f, l = 0.f;

    bf16x8 k0, k1, k2, k3;                   // K prefetch for st = 0
    {
        const u16* kr0 = &Kp[(size_t)lo * HD + hi * 8];
        const u16* kr1 = &Kp[(size_t)(16 + lo) * HD + hi * 8];
        k0 = *(const bf16x8*)&kr0[0];  k1 = *(const bf16x8*)&kr0[32];
        k2 = *(const bf16x8*)&kr1[0];  k3 = *(const bf16x8*)&kr1[32];
    }

    for (int st = 0; st < nst; ++st) {
        const int s0 = st << 5;

        bf16x8 vv[4];                        // V for this tile (issued early)
        #pragma unroll
        for (int dj = 0; dj < 4; ++dj) {
            const u16* vr = &Vp[(size_t)(dj * 16 + lo) * SEQ + s0 + hi * 4];
            union { unsigned long long q[2]; bf16x8 v; } vu;
            vu.q[0] = *(const unsigned long long*)&vr[0];
            vu.q[1] = *(const unsigned long long*)&vr[16];
            vv[dj] = vu.v;
        }

        f32x4 a0 = z, a1 = z;
        __builtin_amdgcn_s_setprio(1);
        a0 = __builtin_amdgcn_mfma_f32_16x16x32_bf16(k0, qf0, a0, 0, 0, 0);
        a0 = __builtin_amdgcn_mfma_f32_16x16x32_bf16(k1, qf1, a0, 0, 0, 0);
        a1 = __builtin_amdgcn_mfma_f32_16x16x32_bf16(k2, qf0, a1, 0, 0, 0);
        a1 = __builtin_amdgcn_mfma_f32_16x16x32_bf16(k3, qf1, a1, 0, 0, 0);
        __builtin_amdgcn_s_setprio(0);

        if (st + 1 < nst) {                  // prefetch K, overlaps softmax
            const u16* kr0 = &Kp[(size_t)(s0 + 32 + lo) * HD + hi * 8];
            const u16* kr1 = &Kp[(size_t)(s0 + 48 + lo) * HD + hi * 8];
            k0 = *(const bf16x8*)&kr0[0];  k1 = *(const bf16x8*)&kr0[32];
            k2 = *(const bf16x8*)&kr1[0];  k3 = *(const bf16x8*)&kr1[32];
        }

        float sc[8];
        #pragma unroll
        for (int e = 0; e < 8; ++e)
            sc[e] = (e < 4) ? a0[e & 3] : a1[e & 3];
        if (st == dT) {
            #pragma unroll
            for (int e = 0; e < 8; ++e) {
                const int srel = ((e >> 2) << 4) + (hi << 2) + (e & 3);
                if (srel > msk0) sc[e] = -3.0e38f;
            }
        }
        float pm = sc[0];
        #pragma unroll
        for (int e = 1; e < 8; ++e) pm = fmaxf(pm, sc[e]);

        if (!__all(pm - m <= 8.0f)) {        // defer-max (per-lane == per-row)
            float pr = fmaxf(pm, __shfl_xor(pm, 16));
            pr = fmaxf(pr, __shfl_xor(pr, 32));
            const float mn = fmaxf(m, pr);
            const float f = exp2f(m - mn);   // first tile: m=-3e38 -> f=0
            l *= f;
            #pragma unroll
            for (int r = 0; r < 4; ++r) {
                const float fr = __shfl(f, hi * 4 + r);
                #pragma unroll
                for (int dj = 0; dj < 4; ++dj) O[dj][r] *= fr;
            }
            m = mn;
        }

        union { u16 u[8]; bf16x8 v; } pu;
        float ps = 0.f;
        #pragma unroll
        for (int e = 0; e < 8; ++e) {
            const float p = exp2f(sc[e] - m);   // bounded by 2^8
            ps += p;
            pu.u[e] = f2bf(p);
        }
        l += ps;                              // per-lane partial

        __builtin_amdgcn_s_setprio(1);
        #pragma unroll
        for (int dj = 0; dj < 4; ++dj)
            O[dj] = __builtin_amdgcn_mfma_f32_16x16x32_bf16(pu.v, vv[dj], O[dj], 0, 0, 0);
        __builtin_amdgcn_s_setprio(0);
    }

    // epilogue: reduce per-lane l across hi-groups, then per-row store
    l += __shfl_xor(l, 16); l += __shfl_xor(l, 32);
    #pragma unroll
    for (int r = 0; r < 4; ++r) {
        const float li = 1.0f / fmaxf(__shfl(l, hi * 4 + r), 1e-37f);
        const int t = q0 + hi * 4 + r;
        #pragma unroll
        for (int dj = 0; dj < 4; ++dj)
            outp[((size_t)(b * SEQ + t)) * DM + h * HD + dj * 16 + lo] = f2bf(O[dj][r] * li);
    }
}

extern "C" void kernel_launch(void* const* d_in, const int* in_sizes, int n_in,
                              void* d_out, int out_size, void* d_ws, size_t ws_size,
                              hipStream_t stream) {
    const float* x   = (const float*)d_in[0];
    const int*   pos = (const int*)d_in[1];
    const float* qw  = (const float*)d_in[2];
    const float* qb  = (const float*)d_in[3];
    const float* kw  = (const float*)d_in[4];
    const float* kb  = (const float*)d_in[5];
    const float* vw  = (const float*)d_in[6];
    const float* vb  = (const float*)d_in[7];
    const float* ow  = (const float*)d_in[8];
    const float* ob  = (const float*)d_in[9];
    float* out = (float*)d_out;                 // OUTPUT IS FP32

    u16* xb    = (u16*)d_ws;                                    // 6291456
    u16* Wqkvt = xb    + (size_t)8192 * DM;                     //  983040
    u16* Wot   = Wqkvt + (size_t)1280 * DM;                     //  589824
    u16* Qbuf  = Wot   + (size_t)DM * DM;                       // 6291456
    u16* Kbuf  = Qbuf  + (size_t)BATCH * NHEAD * SEQ * HD;      // 2097152
    u16* Krot  = Kbuf  + (size_t)BATCH * KVH * SEQ * HD;        // 2097152
    u16* Vtb   = Krot  + (size_t)BATCH * KVH * SEQ * HD;        // 2097152 [b,g,d,s]
    u16* Qrot  = xb;     // alias: xb dead after gemm_qkv
    u16* attn  = Qbuf;   // alias: Qbuf dead after rope

    cvt_x_k<<<(8192 * DM / 4 + 255) / 256, 256, 0, stream>>>(x, xb, 8192 * DM / 4);
    cvt_wqkv_k<<<(1280 * DM + 255) / 256, 256, 0, stream>>>(qw, kw, vw, Wqkvt);
    cvt_wo_k<<<(DM * DM + 255) / 256, 256, 0, stream>>>(ow, Wot);

    gemm_qkv<<<640, 256, 0, stream>>>(xb, Wqkvt, qb, kb, vb, Qbuf, Kbuf, Vtb);

    const long long allrows = (long long)BATCH * (NHEAD + KVH) * SEQ;  // 131072
    rope_naive<<<(int)((allrows * 64 + 255) / 256), 256, 0, stream>>>(
        (const __hip_bfloat16*)Qbuf, (__hip_bfloat16*)Qrot,
        (const __hip_bfloat16*)Kbuf, (__hip_bfloat16*)Krot, pos);

    attn_mfma<<<96 * 16, 256, 0, stream>>>(Qrot, Krot, Vtb, attn);

    gemm_oproj<<<384, 256, 0, stream>>>(attn, Wot, ob, out);
}

// Round 6
// 233.270 us; speedup vs baseline: 1.4516x; 1.4516x over previous
//
#include <hip/hip_runtime.h>
#include <hip/hip_bf16.h>
#include <math.h>

#define BATCH 8
#define SEQ   1024
#define DM    768
#define NHEAD 12
#define KVH   4
#define HD    64
#define REP   3

// softmax scale folded into Q weights, exp2 domain: 0.125 * log2(e)
#define QSCALE 0.18033688011112042f

typedef unsigned short u16;
typedef __attribute__((ext_vector_type(8))) __bf16 bf16x8;
typedef __attribute__((ext_vector_type(4))) float f32x4;
typedef __attribute__((ext_vector_type(4))) unsigned int u32x4;
typedef __attribute__((address_space(1))) const unsigned int gu32_c;
typedef __attribute__((address_space(3))) unsigned int su32;

// RTNE fp32 -> bf16 (finite values)
__device__ __forceinline__ u16 f2bf(float f) {
    unsigned int u = __float_as_uint(f);
    u += 0x7fffu + ((u >> 16) & 1u);
    return (u16)(u >> 16);
}

// ======== convert x -> bf16, vectorized (float4 in, ushort4 out) ============
__global__ __launch_bounds__(256) void cvt_x_k(
    const float* __restrict__ in, u16* __restrict__ o, int n4)
{
    const int i = blockIdx.x * 256 + threadIdx.x;
    if (i >= n4) return;
    const float4 v = ((const float4*)in)[i];
    ushort4 r;
    r.x = f2bf(v.x); r.y = f2bf(v.y); r.z = f2bf(v.z); r.w = f2bf(v.w);
    ((ushort4*)o)[i] = r;
}

// ==== build Wt[n][k] bf16 = concat(qw|kw|vw)[k][n] transposed+converted =====
__global__ __launch_bounds__(256) void cvt_wqkv_k(
    const float* __restrict__ qw, const float* __restrict__ kw,
    const float* __restrict__ vw, u16* __restrict__ wt)
{
    const int idx = blockIdx.x * 256 + threadIdx.x;   // idx = n*768 + k
    if (idx >= 1280 * DM) return;
    const int k = idx % DM;
    const int n = idx / DM;
    float v;
    if (n < 768)       v = qw[(size_t)k * 768 + n] * QSCALE;
    else if (n < 1024) v = kw[(size_t)k * 256 + (n - 768)];
    else               v = vw[(size_t)k * 256 + (n - 1024)];
    wt[idx] = f2bf(v);
}

__global__ __launch_bounds__(256) void cvt_wo_k(
    const float* __restrict__ ow, u16* __restrict__ wt)
{
    const int idx = blockIdx.x * 256 + threadIdx.x;   // idx = n*768 + k
    if (idx >= DM * DM) return;
    const int k = idx % DM;
    const int n = idx / DM;
    wt[idx] = f2bf(ow[(size_t)k * DM + n]);
}

// ======== 128x128-tile bf16 MFMA GEMM body (global_load_lds staging) ========
__device__ __forceinline__ void gemm128_body(
    const u16* __restrict__ A, const u16* __restrict__ B,
    int m0, int n0, u16* As, u16* Bs, f32x4 acc[4][4])
{
    const int tid  = threadIdx.x;
    const int lane = tid & 63;
    const int wid  = tid >> 6;
    const int wr = wid >> 1, wc = wid & 1;
    const int lo = lane & 15, hi = lane >> 4;

    const f32x4 z = {0.f, 0.f, 0.f, 0.f};
    #pragma unroll
    for (int i = 0; i < 4; i++)
        #pragma unroll
        for (int j = 0; j < 4; j++)
            acc[i][j] = z;

    for (int kt = 0; kt < DM; kt += 32) {
        #pragma unroll
        for (int r = 0; r < 2; ++r) {
            const int idx  = r * 256 + tid;           // chunk id, 512 per tile
            const int row  = idx >> 2;
            const int col  = (idx & 3) << 3;
            const int base = (r * 256 + wid * 64) * 8; // wave-uniform LDS elems
            __builtin_amdgcn_global_load_lds(
                (gu32_c*)&A[(size_t)(m0 + row) * DM + kt + col],
                (su32*)&As[base], 16, 0, 0);
            __builtin_amdgcn_global_load_lds(
                (gu32_c*)&B[(size_t)(n0 + row) * DM + kt + col],
                (su32*)&Bs[base], 16, 0, 0);
        }
        __syncthreads();
        bf16x8 af[4], bfr[4];
        #pragma unroll
        for (int i = 0; i < 4; i++) af[i]  = *(const bf16x8*)&As[(wr * 64 + i * 16 + lo) * 32 + hi * 8];
        #pragma unroll
        for (int j = 0; j < 4; j++) bfr[j] = *(const bf16x8*)&Bs[(wc * 64 + j * 16 + lo) * 32 + hi * 8];
        #pragma unroll
        for (int i = 0; i < 4; i++)
            #pragma unroll
            for (int j = 0; j < 4; j++)
                acc[i][j] = __builtin_amdgcn_mfma_f32_16x16x32_bf16(af[i], bfr[j], acc[i][j], 0, 0, 0);
        __syncthreads();
    }
}

// ======== QKV projection -> Q/K head-major [b,h,t,d]; V TRANSPOSED [b,g,d,t]
__global__ __launch_bounds__(256) void gemm_qkv(
    const u16* __restrict__ xb, const u16* __restrict__ wt,
    const float* __restrict__ qb, const float* __restrict__ kb,
    const float* __restrict__ vb,
    u16* __restrict__ Q, u16* __restrict__ K, u16* __restrict__ Vt)
{
    __shared__ __align__(16) u16 As[128 * 32];
    __shared__ __align__(16) u16 Bs[128 * 32];
    const int id = (blockIdx.x & 7) * 80 + (blockIdx.x >> 3);
    const int m0 = (id / 10) * 128;
    const int n0 = (id % 10) * 128;
    f32x4 acc[4][4];
    gemm128_body(xb, wt, m0, n0, As, Bs, acc);

    const int tid = threadIdx.x;
    const int lane = tid & 63, wid = tid >> 6;
    const int wr = wid >> 1, wc = wid & 1;
    const int lo = lane & 15, hi = lane >> 4;

    #pragma unroll
    for (int j = 0; j < 4; j++) {
        const int n = n0 + wc * 64 + j * 16 + lo;
        if (n < 1024) {       // Q or K: [b,h,t,d] layout, scalar stores
            u16* outp; int nl, Hcnt; float bias;
            if (n < 768) { outp = Q; nl = n;       Hcnt = NHEAD; bias = qb[n] * QSCALE; }
            else         { outp = K; nl = n - 768; Hcnt = KVH;   bias = kb[nl]; }
            const int head = nl >> 6, d = nl & 63;
            #pragma unroll
            for (int i = 0; i < 4; i++) {
                #pragma unroll
                for (int r = 0; r < 4; r++) {
                    const int m = m0 + wr * 64 + i * 16 + hi * 4 + r;
                    const int b = m >> 10, t = m & 1023;
                    outp[(((size_t)(b * Hcnt + head)) * SEQ + t) * HD + d] =
                        f2bf(acc[i][j][r] + bias);
                }
            }
        } else {              // V: [b,g,d,t] layout, ushort4 stores
            const int nl = n - 1024;
            const float bias = vb[nl];
            const int head = nl >> 6, d = nl & 63;
            #pragma unroll
            for (int i = 0; i < 4; i++) {
                ushort4 vs;
                vs.x = f2bf(acc[i][j][0] + bias);
                vs.y = f2bf(acc[i][j][1] + bias);
                vs.z = f2bf(acc[i][j][2] + bias);
                vs.w = f2bf(acc[i][j][3] + bias);
                const int m = m0 + wr * 64 + i * 16 + hi * 4;
                const int b = m >> 10, t = m & 1023;
                *(ushort4*)&Vt[(((size_t)(b * KVH + head)) * HD + d) * SEQ + t] = vs;
            }
        }
    }
}

// ======== output projection: attn[8192][768] bf16 @ Wo^T + ob -> fp32 =======
__global__ __launch_bounds__(256) void gemm_oproj(
    const u16* __restrict__ Ab, const u16* __restrict__ wt,
    const float* __restrict__ ob, float* __restrict__ outp)
{
    __shared__ __align__(16) u16 As[128 * 32];
    __shared__ __align__(16) u16 Bs[128 * 32];
    const int id = (blockIdx.x & 7) * 48 + (blockIdx.x >> 3);   // 384 % 8 == 0
    const int m0 = (id / 6) * 128;
    const int n0 = (id % 6) * 128;
    f32x4 acc[4][4];
    gemm128_body(Ab, wt, m0, n0, As, Bs, acc);

    const int tid = threadIdx.x;
    const int lane = tid & 63, wid = tid >> 6;
    const int wr = wid >> 1, wc = wid & 1;
    const int lo = lane & 15, hi = lane >> 4;

    #pragma unroll
    for (int j = 0; j < 4; j++) {
        const int n = n0 + wc * 64 + j * 16 + lo;
        const float bias = ob[n];
        #pragma unroll
        for (int i = 0; i < 4; i++) {
            #pragma unroll
            for (int r = 0; r < 4; r++) {
                const int m = m0 + wr * 64 + i * 16 + hi * 4 + r;
                outp[(size_t)m * DM + n] = acc[i][j][r] + bias;
            }
        }
    }
}

// ======== RoPE, Q and K fused in one launch (file-faithful interleave) ======
__global__ __launch_bounds__(256) void rope_naive(
    const __hip_bfloat16* __restrict__ Qin, __hip_bfloat16* __restrict__ Qout,
    const __hip_bfloat16* __restrict__ Kin, __hip_bfloat16* __restrict__ Kout,
    const int* __restrict__ pos)
{
    const long long qrows = (long long)BATCH * NHEAD * SEQ;   // 98304
    const long long krows = (long long)BATCH * KVH * SEQ;     // 32768
    const long long gid = (long long)blockIdx.x * 256 + threadIdx.x;
    if (gid >= (qrows + krows) * 64) return;
    long long row = gid >> 6;
    const int j = (int)(gid & 63);
    const __hip_bfloat16* in; __hip_bfloat16* outb;
    if (row < qrows) { in = Qin; outb = Qout; }
    else             { in = Kin; outb = Kout; row -= qrows; }
    const int t = (int)(row & (SEQ - 1));

    float p;
    if (pos[1] == 1)                              p = (float)pos[t];
    else if (((const float*)pos)[1] == 1.0f)      p = ((const float*)pos)[t];
    else                                          p = (float)pos[2 * t];

    const float inv = exp2f(-(float)(j & 31) * (13.287712379549449f / 32.0f));
    float sv, cv;
    sincosf(p * inv, &sv, &cv);
    const int partner = (j & 1) * 32 + (j >> 1) + ((j < 32) ? 16 : -16);
    const float sign  = (j < 32) ? -1.0f : 1.0f;
    const float val  = __bfloat162float(in[row * HD + j]);
    const float pv   = __bfloat162float(in[row * HD + partner]);
    outb[row * HD + j] = __float2bfloat16(val * cv + sign * pv * sv);
}

// ======== flash attention v6: block-cooperative LDS-staged K/V ===============
// Block = (b,h) x 8; 4 waves.  Wave w = c + 8*wid owns strip pair
// (sA = 63-w, sB = w) of 16 q-rows each -> near-uniform work; all waves
// active most iterations.  K/V tiles (32 s) staged into LDS double-buffer by
// global_load_lds (DMA: compiler CANNOT sink the prefetch -- the r2..r5
// latency disease).  Prefetch tile st+1 issued before computing tile st;
// __syncthreads (vmcnt(0)+barrier) separates.  K staged with pre-swizzled
// source (16B-unit XOR row&7) -> 4x ds_read_b128 at the 8-round b128 floor.
// V staged at 4B granularity with a source permutation making each lane's
// PV fragment contiguous 16B -> 4x ds_read_b128, bank-optimal.  Fragment
// math identical to verified r5 (swizzles are placement-only).
__device__ __forceinline__ void strip_compute(
    const bf16x8& qf0, const bf16x8& qf1,
    const bf16x8& k0, const bf16x8& k1, const bf16x8& k2, const bf16x8& k3,
    const bf16x8* vv, bool diag, int msk0, int hi,
    float& m, float& l, f32x4* O)
{
    const f32x4 z = {0.f, 0.f, 0.f, 0.f};
    f32x4 a0 = z, a1 = z;
    __builtin_amdgcn_s_setprio(1);
    a0 = __builtin_amdgcn_mfma_f32_16x16x32_bf16(k0, qf0, a0, 0, 0, 0);
    a0 = __builtin_amdgcn_mfma_f32_16x16x32_bf16(k1, qf1, a0, 0, 0, 0);
    a1 = __builtin_amdgcn_mfma_f32_16x16x32_bf16(k2, qf0, a1, 0, 0, 0);
    a1 = __builtin_amdgcn_mfma_f32_16x16x32_bf16(k3, qf1, a1, 0, 0, 0);
    __builtin_amdgcn_s_setprio(0);

    float sc[8];
    #pragma unroll
    for (int e = 0; e < 8; ++e)
        sc[e] = (e < 4) ? a0[e & 3] : a1[e & 3];
    if (diag) {
        #pragma unroll
        for (int e = 0; e < 8; ++e) {
            const int srel = ((e >> 2) << 4) + (hi << 2) + (e & 3);
            if (srel > msk0) sc[e] = -3.0e38f;
        }
    }
    float pm = sc[0];
    #pragma unroll
    for (int e = 1; e < 8; ++e) pm = fmaxf(pm, sc[e]);

    if (!__all(pm - m <= 8.0f)) {            // defer-max (per-lane == per-row)
        float pr = fmaxf(pm, __shfl_xor(pm, 16));
        pr = fmaxf(pr, __shfl_xor(pr, 32));
        const float mn = fmaxf(m, pr);
        const float f = exp2f(m - mn);       // first tile: m=-3e38 -> f=0
        l *= f;
        #pragma unroll
        for (int r = 0; r < 4; ++r) {
            const float fr = __shfl(f, hi * 4 + r);
            #pragma unroll
            for (int dj = 0; dj < 4; ++dj) O[dj][r] *= fr;
        }
        m = mn;
    }

    union { u16 u[8]; bf16x8 v; } pu;
    float ps = 0.f;
    #pragma unroll
    for (int e = 0; e < 8; ++e) {
        const float p = exp2f(sc[e] - m);    // bounded by 2^8
        ps += p;
        pu.u[e] = f2bf(p);
    }
    l += ps;                                  // per-lane partial

    __builtin_amdgcn_s_setprio(1);
    #pragma unroll
    for (int dj = 0; dj < 4; ++dj)
        O[dj] = __builtin_amdgcn_mfma_f32_16x16x32_bf16(pu.v, vv[dj], O[dj], 0, 0, 0);
    __builtin_amdgcn_s_setprio(0);
}

__global__ __launch_bounds__(256, 2) void attn_mfma(
    const u16* __restrict__ Q, const u16* __restrict__ K,
    const u16* __restrict__ Vt, u16* __restrict__ outp)
{
    __shared__ __align__(16) u16 Ks[2][2048];   // 32 s x 64 d, swizzled
    __shared__ __align__(16) u16 Vs[2][2048];   // 64 d x 32 s, permuted

    const int wg = (blockIdx.x & 7) * 96 + (blockIdx.x >> 3);   // XCD swizzle
    const int bh = wg >> 3;
    const int c  = wg & 7;
    const int b  = bh / NHEAD, h = bh % NHEAD;
    const int g  = h / REP;
    const int wid  = threadIdx.x >> 6;
    const int lane = threadIdx.x & 63;
    const int lo = lane & 15, hi = lane >> 4;

    const int w    = c + (wid << 3);             // 0..31
    const int sA   = 63 - w, sB = w;             // strip pair (16 rows each)
    const int dA   = sA >> 1, dB = sB >> 1;      // diagonal tile indices
    const int mskA = lo + ((sA & 1) << 4);
    const int mskB = lo + ((sB & 1) << 4);
    const int nstT = ((63 - c) >> 1) + 1;        // block-uniform trip count

    const u16* Kp = K  + (size_t)(b * KVH + g) * SEQ * HD;
    const u16* Vp = Vt + (size_t)(b * KVH + g) * SEQ * HD;   // [d][s]

    // --- staging address constants (per lane, tile-invariant) ---
    // K: 16B units j; dest linear j = wid*64+lane; src unit = j ^ ((j>>3)&7)
    const int jK = (wid << 6) + lane;
    const int sKoff = (jK ^ ((jK >> 3) & 7)) << 3;           // u16 offset
    // V: 4B dwords; dest dw = wid*256 + q*64 + lane; src elem offset:
    int vsoff[4];
    #pragma unroll
    for (int q = 0; q < 4; ++q) {
        const int dw  = (wid << 8) + (q << 6) + lane;
        const int R   = dw >> 4;
        const int wd  = dw & 15;
        const int c8p = wd >> 1, ii = wd & 1;
        const int sc8 = (c8p >> 1) + ((c8p & 1) << 2);
        vsoff[q] = (R << 10) + (((sc8 << 1) + ii) << 1);     // u16 offset (+s0)
    }

    // Q fragments for both strips
    const u16* QpA = Q + ((size_t)(b * NHEAD + h) * SEQ + (sA << 4)) * HD;
    const u16* QpB = Q + ((size_t)(b * NHEAD + h) * SEQ + (sB << 4)) * HD;
    const bf16x8 qA0 = *(const bf16x8*)&QpA[(size_t)lo * HD + hi * 8];
    const bf16x8 qA1 = *(const bf16x8*)&QpA[(size_t)lo * HD + 32 + hi * 8];
    const bf16x8 qB0 = *(const bf16x8*)&QpB[(size_t)lo * HD + hi * 8];
    const bf16x8 qB1 = *(const bf16x8*)&QpB[(size_t)lo * HD + 32 + hi * 8];

    const f32x4 z = {0.f, 0.f, 0.f, 0.f};
    f32x4 OA[4], OB[4];
    #pragma unroll
    for (int dj = 0; dj < 4; ++dj) { OA[dj] = z; OB[dj] = z; }
    float mA = -3.0e38f, lA = 0.f, mB = -3.0e38f, lB = 0.f;

    // stage tile st into buffer bf
    #define STAGE(st_, bf_) do {                                              \
        const int s0_ = (st_) << 5;                                           \
        __builtin_amdgcn_global_load_lds(                                     \
            (gu32_c*)(Kp + (s0_ << 6) + sKoff),                               \
            (su32*)&Ks[bf_][wid << 9], 16, 0, 0);                             \
        _Pragma("unroll")                                                     \
        for (int q_ = 0; q_ < 4; ++q_)                                        \
            __builtin_amdgcn_global_load_lds(                                 \
                (gu32_c*)(Vp + s0_ + vsoff[q_]),                              \
                (su32*)&Vs[bf_][(wid << 9) + (q_ << 7)], 4, 0, 0);            \
    } while (0)

    STAGE(0, 0);
    __syncthreads();

    const int xorK = lo & 7;
    for (int st = 0; st < nstT; ++st) {
        const int buf = st & 1;
        if (st + 1 < nstT) STAGE(st + 1, buf ^ 1);

        if (st <= dA) {
            const u16* kb_ = Ks[buf];
            const bf16x8 k0 = *(const bf16x8*)&kb_[((lo << 3) + (hi ^ xorK)) << 3];
            const bf16x8 k1 = *(const bf16x8*)&kb_[((lo << 3) + ((4 + hi) ^ xorK)) << 3];
            const bf16x8 k2 = *(const bf16x8*)&kb_[(((16 + lo) << 3) + (hi ^ xorK)) << 3];
            const bf16x8 k3 = *(const bf16x8*)&kb_[(((16 + lo) << 3) + ((4 + hi) ^ xorK)) << 3];
            bf16x8 vv[4];
            #pragma unroll
            for (int dj = 0; dj < 4; ++dj)
                vv[dj] = *(const bf16x8*)&Vs[buf][((dj * 16 + lo) << 5) + (hi << 3)];

            strip_compute(qA0, qA1, k0, k1, k2, k3, vv, st == dA, mskA, hi, mA, lA, OA);
            if (st <= dB)
                strip_compute(qB0, qB1, k0, k1, k2, k3, vv, st == dB, mskB, hi, mB, lB, OB);
        }
        __syncthreads();
    }
    #undef STAGE

    // epilogue: reduce per-lane l across hi-groups, then per-row store
    lA += __shfl_xor(lA, 16); lA += __shfl_xor(lA, 32);
    lB += __shfl_xor(lB, 16); lB += __shfl_xor(lB, 32);
    #pragma unroll
    for (int r = 0; r < 4; ++r) {
        const float liA = 1.0f / fmaxf(__shfl(lA, hi * 4 + r), 1e-37f);
        const float liB = 1.0f / fmaxf(__shfl(lB, hi * 4 + r), 1e-37f);
        const int tA = (sA << 4) + hi * 4 + r;
        const int tB = (sB << 4) + hi * 4 + r;
        #pragma unroll
        for (int dj = 0; dj < 4; ++dj) {
            outp[((size_t)(b * SEQ + tA)) * DM + h * HD + dj * 16 + lo] = f2bf(OA[dj][r] * liA);
            outp[((size_t)(b * SEQ + tB)) * DM + h * HD + dj * 16 + lo] = f2bf(OB[dj][r] * liB);
        }
    }
}

extern "C" void kernel_launch(void* const* d_in, const int* in_sizes, int n_in,
                              void* d_out, int out_size, void* d_ws, size_t ws_size,
                              hipStream_t stream) {
    const float* x   = (const float*)d_in[0];
    const int*   pos = (const int*)d_in[1];
    const float* qw  = (const float*)d_in[2];
    const float* qb  = (const float*)d_in[3];
    const float* kw  = (const float*)d_in[4];
    const float* kb  = (const float*)d_in[5];
    const float* vw  = (const float*)d_in[6];
    const float* vb  = (const float*)d_in[7];
    const float* ow  = (const float*)d_in[8];
    const float* ob  = (const float*)d_in[9];
    float* out = (float*)d_out;                 // OUTPUT IS FP32

    u16* xb    = (u16*)d_ws;                                    // 6291456
    u16* Wqkvt = xb    + (size_t)8192 * DM;                     //  983040
    u16* Wot   = Wqkvt + (size_t)1280 * DM;                     //  589824
    u16* Qbuf  = Wot   + (size_t)DM * DM;                       // 6291456
    u16* Kbuf  = Qbuf  + (size_t)BATCH * NHEAD * SEQ * HD;      // 2097152
    u16* Krot  = Kbuf  + (size_t)BATCH * KVH * SEQ * HD;        // 2097152
    u16* Vtb   = Krot  + (size_t)BATCH * KVH * SEQ * HD;        // 2097152 [b,g,d,s]
    u16* Qrot  = xb;     // alias: xb dead after gemm_qkv
    u16* attn  = Qbuf;   // alias: Qbuf dead after rope

    cvt_x_k<<<(8192 * DM / 4 + 255) / 256, 256, 0, stream>>>(x, xb, 8192 * DM / 4);
    cvt_wqkv_k<<<(1280 * DM + 255) / 256, 256, 0, stream>>>(qw, kw, vw, Wqkvt);
    cvt_wo_k<<<(DM * DM + 255) / 256, 256, 0, stream>>>(ow, Wot);

    gemm_qkv<<<640, 256, 0, stream>>>(xb, Wqkvt, qb, kb, vb, Qbuf, Kbuf, Vtb);

    const long long allrows = (long long)BATCH * (NHEAD + KVH) * SEQ;  // 131072
    rope_naive<<<(int)((allrows * 64 + 255) / 256), 256, 0, stream>>>(
        (const __hip_bfloat16*)Qbuf, (__hip_bfloat16*)Qrot,
        (const __hip_bfloat16*)Kbuf, (__hip_bfloat16*)Krot, pos);

    attn_mfma<<<96 * 8, 256, 0, stream>>>(Qrot, Krot, Vtb, attn);

    gemm_oproj<<<384, 256, 0, stream>>>(attn, Wot, ob, out);
}

// Round 8
// 232.702 us; speedup vs baseline: 1.4552x; 1.0024x over previous
//
#include <hip/hip_runtime.h>
#include <hip/hip_bf16.h>
#include <math.h>

#define BATCH 8
#define SEQ   1024
#define DM    768
#define NHEAD 12
#define KVH   4
#define HD    64
#define REP   3

// softmax scale folded into Q weights, exp2 domain: 0.125 * log2(e)
#define QSCALE 0.18033688011112042f

typedef unsigned short u16;
typedef __attribute__((ext_vector_type(8))) __bf16 bf16x8;
typedef __attribute__((ext_vector_type(4))) float f32x4;
typedef __attribute__((ext_vector_type(4))) unsigned int u32x4;
typedef __attribute__((address_space(1))) const unsigned int gu32_c;
typedef __attribute__((address_space(3))) unsigned int su32;

// RTNE fp32 -> bf16 (finite values)
__device__ __forceinline__ u16 f2bf(float f) {
    unsigned int u = __float_as_uint(f);
    u += 0x7fffu + ((u >> 16) & 1u);
    return (u16)(u >> 16);
}

// ======== convert x -> bf16, vectorized (float4 in, ushort4 out) ============
__global__ __launch_bounds__(256) void cvt_x_k(
    const float* __restrict__ in, u16* __restrict__ o, int n4)
{
    const int i = blockIdx.x * 256 + threadIdx.x;
    if (i >= n4) return;
    const float4 v = ((const float4*)in)[i];
    ushort4 r;
    r.x = f2bf(v.x); r.y = f2bf(v.y); r.z = f2bf(v.z); r.w = f2bf(v.w);
    ((ushort4*)o)[i] = r;
}

// ==== build Wt[n][k] bf16 = concat(qw|kw|vw)[k][n] transposed+converted =====
__global__ __launch_bounds__(256) void cvt_wqkv_k(
    const float* __restrict__ qw, const float* __restrict__ kw,
    const float* __restrict__ vw, u16* __restrict__ wt)
{
    const int idx = blockIdx.x * 256 + threadIdx.x;   // idx = n*768 + k
    if (idx >= 1280 * DM) return;
    const int k = idx % DM;
    const int n = idx / DM;
    float v;
    if (n < 768)       v = qw[(size_t)k * 768 + n] * QSCALE;
    else if (n < 1024) v = kw[(size_t)k * 256 + (n - 768)];
    else               v = vw[(size_t)k * 256 + (n - 1024)];
    wt[idx] = f2bf(v);
}

__global__ __launch_bounds__(256) void cvt_wo_k(
    const float* __restrict__ ow, u16* __restrict__ wt)
{
    const int idx = blockIdx.x * 256 + threadIdx.x;   // idx = n*768 + k
    if (idx >= DM * DM) return;
    const int k = idx % DM;
    const int n = idx / DM;
    wt[idx] = f2bf(ow[(size_t)k * DM + n]);
}

// ======== 128x128-tile bf16 MFMA GEMM body (global_load_lds staging) ========
__device__ __forceinline__ void gemm128_body(
    const u16* __restrict__ A, const u16* __restrict__ B,
    int m0, int n0, u16* As, u16* Bs, f32x4 acc[4][4])
{
    const int tid  = threadIdx.x;
    const int lane = tid & 63;
    const int wid  = tid >> 6;
    const int wr = wid >> 1, wc = wid & 1;
    const int lo = lane & 15, hi = lane >> 4;

    const f32x4 z = {0.f, 0.f, 0.f, 0.f};
    #pragma unroll
    for (int i = 0; i < 4; i++)
        #pragma unroll
        for (int j = 0; j < 4; j++)
            acc[i][j] = z;

    for (int kt = 0; kt < DM; kt += 32) {
        #pragma unroll
        for (int r = 0; r < 2; ++r) {
            const int idx  = r * 256 + tid;           // chunk id, 512 per tile
            const int row  = idx >> 2;
            const int col  = (idx & 3) << 3;
            const int base = (r * 256 + wid * 64) * 8; // wave-uniform LDS elems
            __builtin_amdgcn_global_load_lds(
                (gu32_c*)&A[(size_t)(m0 + row) * DM + kt + col],
                (su32*)&As[base], 16, 0, 0);
            __builtin_amdgcn_global_load_lds(
                (gu32_c*)&B[(size_t)(n0 + row) * DM + kt + col],
                (su32*)&Bs[base], 16, 0, 0);
        }
        __syncthreads();
        bf16x8 af[4], bfr[4];
        #pragma unroll
        for (int i = 0; i < 4; i++) af[i]  = *(const bf16x8*)&As[(wr * 64 + i * 16 + lo) * 32 + hi * 8];
        #pragma unroll
        for (int j = 0; j < 4; j++) bfr[j] = *(const bf16x8*)&Bs[(wc * 64 + j * 16 + lo) * 32 + hi * 8];
        #pragma unroll
        for (int i = 0; i < 4; i++)
            #pragma unroll
            for (int j = 0; j < 4; j++)
                acc[i][j] = __builtin_amdgcn_mfma_f32_16x16x32_bf16(af[i], bfr[j], acc[i][j], 0, 0, 0);
        __syncthreads();
    }
}

// ======== QKV projection -> Q/K/V ALL head-major [b,H,t,d] coalesced ========
// (round-1-proven store pattern; V transposed later by vtrans_k)
__global__ __launch_bounds__(256) void gemm_qkv(
    const u16* __restrict__ xb, const u16* __restrict__ wt,
    const float* __restrict__ qb, const float* __restrict__ kb,
    const float* __restrict__ vb,
    u16* __restrict__ Q, u16* __restrict__ K, u16* __restrict__ Vr)
{
    __shared__ __align__(16) u16 As[128 * 32];
    __shared__ __align__(16) u16 Bs[128 * 32];
    const int id = (blockIdx.x & 7) * 80 + (blockIdx.x >> 3);
    const int m0 = (id / 10) * 128;
    const int n0 = (id % 10) * 128;
    f32x4 acc[4][4];
    gemm128_body(xb, wt, m0, n0, As, Bs, acc);

    const int tid = threadIdx.x;
    const int lane = tid & 63, wid = tid >> 6;
    const int wr = wid >> 1, wc = wid & 1;
    const int lo = lane & 15, hi = lane >> 4;

    #pragma unroll
    for (int j = 0; j < 4; j++) {
        const int n = n0 + wc * 64 + j * 16 + lo;
        u16* outp; int nl, Hcnt; float bias;
        if (n < 768)       { outp = Q;  nl = n;        Hcnt = NHEAD; bias = qb[n] * QSCALE; }
        else if (n < 1024) { outp = K;  nl = n - 768;  Hcnt = KVH;   bias = kb[nl]; }
        else               { outp = Vr; nl = n - 1024; Hcnt = KVH;   bias = vb[nl]; }
        const int head = nl >> 6, d = nl & 63;
        #pragma unroll
        for (int i = 0; i < 4; i++) {
            #pragma unroll
            for (int r = 0; r < 4; r++) {
                const int m = m0 + wr * 64 + i * 16 + hi * 4 + r;
                const int b = m >> 10, t = m & 1023;
                outp[(((size_t)(b * Hcnt + head)) * SEQ + t) * HD + d] =
                    f2bf(acc[i][j][r] + bias);
            }
        }
    }
}

// ======== V transpose: [b,g,t,d] -> [b,g,d,t] via LDS bounce ================
// FIXED (r7 bug): store was one u32x4 (8 u16) but tc strides by 16 -> half of
// the output was never written.  Now two u32x4 stores per thread (16 u16).
__global__ __launch_bounds__(256) void vtrans_k(
    const u16* __restrict__ in, u16* __restrict__ out)
{
    __shared__ u16 T[64][72];                 // 144B row stride = 9x16B: aligned
    const int blk = blockIdx.x;               // 32 (b,g) x 16 t-tiles = 512
    const int bg  = blk >> 4;
    const int t0  = (blk & 15) << 6;
    const int tid = threadIdx.x;
    const int tl  = tid & 63;
    const int d0  = (tid >> 6) << 4;          // 0,16,32,48

    union { u32x4 v[2]; u16 u[16]; } ld;
    const u16* src = in + ((size_t)bg * SEQ + t0 + tl) * HD + d0;
    ld.v[0] = *(const u32x4*)(src);
    ld.v[1] = *(const u32x4*)(src + 8);
    #pragma unroll
    for (int k = 0; k < 16; ++k) T[d0 + k][tl] = ld.u[k];
    __syncthreads();

    const int d  = tid >> 2;
    const int tc = (tid & 3) << 4;
    u16* dst = out + ((size_t)bg * HD + d) * SEQ + t0 + tc;
    *(u32x4*)(dst)     = *(const u32x4*)&T[d][tc];
    *(u32x4*)(dst + 8) = *(const u32x4*)&T[d][tc + 8];
}

// ======== output projection: attn[8192][768] bf16 @ Wo^T + ob -> fp32 =======
__global__ __launch_bounds__(256) void gemm_oproj(
    const u16* __restrict__ Ab, const u16* __restrict__ wt,
    const float* __restrict__ ob, float* __restrict__ outp)
{
    __shared__ __align__(16) u16 As[128 * 32];
    __shared__ __align__(16) u16 Bs[128 * 32];
    const int id = (blockIdx.x & 7) * 48 + (blockIdx.x >> 3);   // 384 % 8 == 0
    const int m0 = (id / 6) * 128;
    const int n0 = (id % 6) * 128;
    f32x4 acc[4][4];
    gemm128_body(Ab, wt, m0, n0, As, Bs, acc);

    const int tid = threadIdx.x;
    const int lane = tid & 63, wid = tid >> 6;
    const int wr = wid >> 1, wc = wid & 1;
    const int lo = lane & 15, hi = lane >> 4;

    #pragma unroll
    for (int j = 0; j < 4; j++) {
        const int n = n0 + wc * 64 + j * 16 + lo;
        const float bias = ob[n];
        #pragma unroll
        for (int i = 0; i < 4; i++) {
            #pragma unroll
            for (int r = 0; r < 4; r++) {
                const int m = m0 + wr * 64 + i * 16 + hi * 4 + r;
                outp[(size_t)m * DM + n] = acc[i][j][r] + bias;
            }
        }
    }
}

// ======== RoPE, Q and K fused in one launch (file-faithful interleave) ======
__global__ __launch_bounds__(256) void rope_naive(
    const __hip_bfloat16* __restrict__ Qin, __hip_bfloat16* __restrict__ Qout,
    const __hip_bfloat16* __restrict__ Kin, __hip_bfloat16* __restrict__ Kout,
    const int* __restrict__ pos)
{
    const long long qrows = (long long)BATCH * NHEAD * SEQ;   // 98304
    const long long krows = (long long)BATCH * KVH * SEQ;     // 32768
    const long long gid = (long long)blockIdx.x * 256 + threadIdx.x;
    if (gid >= (qrows + krows) * 64) return;
    long long row = gid >> 6;
    const int j = (int)(gid & 63);
    const __hip_bfloat16* in; __hip_bfloat16* outb;
    if (row < qrows) { in = Qin; outb = Qout; }
    else             { in = Kin; outb = Kout; row -= qrows; }
    const int t = (int)(row & (SEQ - 1));

    float p;
    if (pos[1] == 1)                              p = (float)pos[t];
    else if (((const float*)pos)[1] == 1.0f)      p = ((const float*)pos)[t];
    else                                          p = (float)pos[2 * t];

    const float inv = exp2f(-(float)(j & 31) * (13.287712379549449f / 32.0f));
    float sv, cv;
    sincosf(p * inv, &sv, &cv);
    const int partner = (j & 1) * 32 + (j >> 1) + ((j < 32) ? 16 : -16);
    const float sign  = (j < 32) ? -1.0f : 1.0f;
    const float val  = __bfloat162float(in[row * HD + j]);
    const float pv   = __bfloat162float(in[row * HD + partner]);
    outb[row * HD + j] = __float2bfloat16(val * cv + sign * pv * sv);
}

// ======== flash attention v7: 1536 blocks, single strip/wave ================
// Grid 96 (b,h) x 16 slices; 4 waves.  Wave strip w = c + 16*wid (16 q-rows).
// 24 waves/CU static (vs 12 in v6) -> the QK->softmax->PV serial chain hides
// across peer waves.  K/V staged by global_load_lds double-buffer (v6 scheme).
__device__ __forceinline__ void strip_compute(
    const bf16x8& qf0, const bf16x8& qf1,
    const bf16x8& k0, const bf16x8& k1, const bf16x8& k2, const bf16x8& k3,
    const bf16x8* vv, bool diag, int msk0, int hi,
    float& m, float& l, f32x4* O)
{
    const f32x4 z = {0.f, 0.f, 0.f, 0.f};
    f32x4 a0 = z, a1 = z;
    __builtin_amdgcn_s_setprio(1);
    a0 = __builtin_amdgcn_mfma_f32_16x16x32_bf16(k0, qf0, a0, 0, 0, 0);
    a0 = __builtin_amdgcn_mfma_f32_16x16x32_bf16(k1, qf1, a0, 0, 0, 0);
    a1 = __builtin_amdgcn_mfma_f32_16x16x32_bf16(k2, qf0, a1, 0, 0, 0);
    a1 = __builtin_amdgcn_mfma_f32_16x16x32_bf16(k3, qf1, a1, 0, 0, 0);
    __builtin_amdgcn_s_setprio(0);

    float sc[8];
    #pragma unroll
    for (int e = 0; e < 8; ++e)
        sc[e] = (e < 4) ? a0[e & 3] : a1[e & 3];
    if (diag) {
        #pragma unroll
        for (int e = 0; e < 8; ++e) {
            const int srel = ((e >> 2) << 4) + (hi << 2) + (e & 3);
            if (srel > msk0) sc[e] = -3.0e38f;
        }
    }
    float pm = sc[0];
    #pragma unroll
    for (int e = 1; e < 8; ++e) pm = fmaxf(pm, sc[e]);

    if (!__all(pm - m <= 8.0f)) {            // defer-max (per-lane == per-row)
        float pr = fmaxf(pm, __shfl_xor(pm, 16));
        pr = fmaxf(pr, __shfl_xor(pr, 32));
        const float mn = fmaxf(m, pr);
        const float f = exp2f(m - mn);       // first tile: m=-3e38 -> f=0
        l *= f;
        #pragma unroll
        for (int r = 0; r < 4; ++r) {
            const float fr = __shfl(f, hi * 4 + r);
            #pragma unroll
            for (int dj = 0; dj < 4; ++dj) O[dj][r] *= fr;
        }
        m = mn;
    }

    union { u16 u[8]; bf16x8 v; } pu;
    float ps = 0.f;
    #pragma unroll
    for (int e = 0; e < 8; ++e) {
        const float p = exp2f(sc[e] - m);    // bounded by 2^8
        ps += p;
        pu.u[e] = f2bf(p);
    }
    l += ps;                                  // per-lane partial

    __builtin_amdgcn_s_setprio(1);
    #pragma unroll
    for (int dj = 0; dj < 4; ++dj)
        O[dj] = __builtin_amdgcn_mfma_f32_16x16x32_bf16(pu.v, vv[dj], O[dj], 0, 0, 0);
    __builtin_amdgcn_s_setprio(0);
}

__global__ __launch_bounds__(256, 4) void attn_mfma(
    const u16* __restrict__ Q, const u16* __restrict__ K,
    const u16* __restrict__ Vt, u16* __restrict__ outp)
{
    __shared__ __align__(16) u16 Ks[2][2048];   // 32 s x 64 d, swizzled
    __shared__ __align__(16) u16 Vs[2][2048];   // 64 d x 32 s, perm+XOR swizzled

    const int wg = (blockIdx.x & 7) * 192 + (blockIdx.x >> 3);  // XCD swizzle
    const int bh = wg >> 4;
    const int c  = wg & 15;
    const int b  = bh / NHEAD, h = bh % NHEAD;
    const int g  = h / REP;
    const int wid  = threadIdx.x >> 6;
    const int lane = threadIdx.x & 63;
    const int lo = lane & 15, hi = lane >> 4;

    const int w    = c + (wid << 4);             // strip 0..63 (16 q-rows)
    const int q0   = w << 4;
    const int dT   = w >> 1;                     // last tile for this strip
    const int msk0 = lo + ((w & 1) << 4);
    const int nstT = ((c + 48) >> 1) + 1;        // block-uniform trip count

    const u16* Kp = K  + (size_t)(b * KVH + g) * SEQ * HD;
    const u16* Vp = Vt + (size_t)(b * KVH + g) * SEQ * HD;   // [d][s]

    // --- staging address constants (per lane, tile-invariant) ---
    // K: 16B units j; dest linear j = wid*64+lane; src unit = j ^ ((j>>3)&7)
    const int jK = (wid << 6) + lane;
    const int sKoff = (jK ^ ((jK >> 3) & 7)) << 3;           // u16 offset
    // V: 4B dwords; dest dw = wid*256 + q*64 + lane.
    // dest (R, wd): granule gd = wd>>2 holds logical granule gd ^ ((R>>1)&3);
    // logical u16 perm: s = 4*hpl + 16*((wd>>1)&1) + 2*(wd&1) (+elem).
    int vsoff[4];
    #pragma unroll
    for (int q = 0; q < 4; ++q) {
        const int dw  = (wid << 8) + (q << 6) + lane;
        const int R   = dw >> 4;
        const int wd  = dw & 15;
        const int hpl = (wd >> 2) ^ ((R >> 1) & 3);
        vsoff[q] = (R << 10) + (hpl << 2) + (((wd >> 1) & 1) << 4) + ((wd & 1) << 1);
    }

    const u16* Qp = Q + ((size_t)(b * NHEAD + h) * SEQ + q0) * HD;
    const bf16x8 qf0 = *(const bf16x8*)&Qp[(size_t)lo * HD + hi * 8];
    const bf16x8 qf1 = *(const bf16x8*)&Qp[(size_t)lo * HD + 32 + hi * 8];

    const f32x4 z = {0.f, 0.f, 0.f, 0.f};
    f32x4 O[4];
    #pragma unroll
    for (int dj = 0; dj < 4; ++dj) O[dj] = z;
    float m = -3.0e38f, l = 0.f;

    #define STAGE(st_, bf_) do {                                              \
        const int s0_ = (st_) << 5;                                           \
        __builtin_amdgcn_global_load_lds(                                     \
            (gu32_c*)(Kp + (s0_ << 6) + sKoff),                               \
            (su32*)&Ks[bf_][wid << 9], 16, 0, 0);                             \
        _Pragma("unroll")                                                     \
        for (int q_ = 0; q_ < 4; ++q_)                                        \
            __builtin_amdgcn_global_load_lds(                                 \
                (gu32_c*)(Vp + s0_ + vsoff[q_]),                              \
                (su32*)&Vs[bf_][(wid << 9) + (q_ << 7)], 4, 0, 0);            \
    } while (0)

    STAGE(0, 0);
    __syncthreads();

    const int xorK = lo & 7;
    for (int st = 0; st < nstT; ++st) {
        const int buf = st & 1;
        if (st + 1 < nstT) STAGE(st + 1, buf ^ 1);

        if (st <= dT) {
            const u16* kb_ = Ks[buf];
            const bf16x8 k0 = *(const bf16x8*)&kb_[((lo << 3) + (hi ^ xorK)) << 3];
            const bf16x8 k1 = *(const bf16x8*)&kb_[((lo << 3) + ((4 + hi) ^ xorK)) << 3];
            const bf16x8 k2 = *(const bf16x8*)&kb_[(((16 + lo) << 3) + (hi ^ xorK)) << 3];
            const bf16x8 k3 = *(const bf16x8*)&kb_[(((16 + lo) << 3) + ((4 + hi) ^ xorK)) << 3];
            bf16x8 vv[4];
            #pragma unroll
            for (int dj = 0; dj < 4; ++dj) {
                const int R = dj * 16 + lo;
                vv[dj] = *(const bf16x8*)&Vs[buf][(R << 5) + ((hi ^ ((R >> 1) & 3)) << 3)];
            }
            strip_compute(qf0, qf1, k0, k1, k2, k3, vv, st == dT, msk0, hi, m, l, O);
        }
        __syncthreads();
    }
    #undef STAGE

    // epilogue: reduce per-lane l across hi-groups, then per-row store
    l += __shfl_xor(l, 16); l += __shfl_xor(l, 32);
    #pragma unroll
    for (int r = 0; r < 4; ++r) {
        const float li = 1.0f / fmaxf(__shfl(l, hi * 4 + r), 1e-37f);
        const int t = q0 + hi * 4 + r;
        #pragma unroll
        for (int dj = 0; dj < 4; ++dj)
            outp[((size_t)(b * SEQ + t)) * DM + h * HD + dj * 16 + lo] = f2bf(O[dj][r] * li);
    }
}

extern "C" void kernel_launch(void* const* d_in, const int* in_sizes, int n_in,
                              void* d_out, int out_size, void* d_ws, size_t ws_size,
                              hipStream_t stream) {
    const float* x   = (const float*)d_in[0];
    const int*   pos = (const int*)d_in[1];
    const float* qw  = (const float*)d_in[2];
    const float* qb  = (const float*)d_in[3];
    const float* kw  = (const float*)d_in[4];
    const float* kb  = (const float*)d_in[5];
    const float* vw  = (const float*)d_in[6];
    const float* vb  = (const float*)d_in[7];
    const float* ow  = (const float*)d_in[8];
    const float* ob  = (const float*)d_in[9];
    float* out = (float*)d_out;                 // OUTPUT IS FP32

    u16* xb    = (u16*)d_ws;                                    // 6291456
    u16* Wqkvt = xb    + (size_t)8192 * DM;                     //  983040
    u16* Wot   = Wqkvt + (size_t)1280 * DM;                     //  589824
    u16* Qbuf  = Wot   + (size_t)DM * DM;                       // 6291456
    u16* Kbuf  = Qbuf  + (size_t)BATCH * NHEAD * SEQ * HD;      // 2097152
    u16* Krot  = Kbuf  + (size_t)BATCH * KVH * SEQ * HD;        // 2097152
    u16* Vtb   = Krot  + (size_t)BATCH * KVH * SEQ * HD;        // 2097152 [b,g,d,s]
    u16* Qrot  = xb;     // alias: xb dead after gemm_qkv
    u16* attn  = Qbuf;   // alias: Qbuf dead after rope
    u16* Vraw  = Krot;   // alias: [b,g,t,d], dead after vtrans (before rope writes Krot)

    cvt_x_k<<<(8192 * DM / 4 + 255) / 256, 256, 0, stream>>>(x, xb, 8192 * DM / 4);
    cvt_wqkv_k<<<(1280 * DM + 255) / 256, 256, 0, stream>>>(qw, kw, vw, Wqkvt);
    cvt_wo_k<<<(DM * DM + 255) / 256, 256, 0, stream>>>(ow, Wot);

    gemm_qkv<<<640, 256, 0, stream>>>(xb, Wqkvt, qb, kb, vb, Qbuf, Kbuf, Vraw);

    vtrans_k<<<512, 256, 0, stream>>>(Vraw, Vtb);   // before rope overwrites Krot

    const long long allrows = (long long)BATCH * (NHEAD + KVH) * SEQ;  // 131072
    rope_naive<<<(int)((allrows * 64 + 255) / 256), 256, 0, stream>>>(
        (const __hip_bfloat16*)Qbuf, (__hip_bfloat16*)Qrot,
        (const __hip_bfloat16*)Kbuf, (__hip_bfloat16*)Krot, pos);

    attn_mfma<<<96 * 16, 256, 0, stream>>>(Qrot, Krot, Vtb, attn);

    gemm_oproj<<<384, 256, 0, stream>>>(attn, Wot, ob, out);
}

// Round 9
// 229.789 us; speedup vs baseline: 1.4736x; 1.0127x over previous
//
#include <hip/hip_runtime.h>
#include <hip/hip_bf16.h>
#include <math.h>

#define BATCH 8
#define SEQ   1024
#define DM    768
#define NHEAD 12
#define KVH   4
#define HD    64
#define REP   3

// softmax scale folded into Q weights, exp2 domain: 0.125 * log2(e)
#define QSCALE 0.18033688011112042f

typedef unsigned short u16;
typedef __attribute__((ext_vector_type(8))) __bf16 bf16x8;
typedef __attribute__((ext_vector_type(4))) float f32x4;
typedef __attribute__((ext_vector_type(4))) unsigned int u32x4;
typedef __attribute__((address_space(1))) const unsigned int gu32_c;
typedef __attribute__((address_space(3))) unsigned int su32;

// RTNE fp32 -> bf16 (finite values)
__device__ __forceinline__ u16 f2bf(float f) {
    unsigned int u = __float_as_uint(f);
    u += 0x7fffu + ((u >> 16) & 1u);
    return (u16)(u >> 16);
}

// ======== convert x -> bf16, vectorized (float4 in, ushort4 out) ============
__global__ __launch_bounds__(256) void cvt_x_k(
    const float* __restrict__ in, u16* __restrict__ o, int n4)
{
    const int i = blockIdx.x * 256 + threadIdx.x;
    if (i >= n4) return;
    const float4 v = ((const float4*)in)[i];
    ushort4 r;
    r.x = f2bf(v.x); r.y = f2bf(v.y); r.z = f2bf(v.z); r.w = f2bf(v.w);
    ((ushort4*)o)[i] = r;
}

// ==== build Wt[n][k] bf16 = concat(qw|kw|vw)[k][n] transposed+converted =====
__global__ __launch_bounds__(256) void cvt_wqkv_k(
    const float* __restrict__ qw, const float* __restrict__ kw,
    const float* __restrict__ vw, u16* __restrict__ wt)
{
    const int idx = blockIdx.x * 256 + threadIdx.x;   // idx = n*768 + k
    if (idx >= 1280 * DM) return;
    const int k = idx % DM;
    const int n = idx / DM;
    float v;
    if (n < 768)       v = qw[(size_t)k * 768 + n] * QSCALE;
    else if (n < 1024) v = kw[(size_t)k * 256 + (n - 768)];
    else               v = vw[(size_t)k * 256 + (n - 1024)];
    wt[idx] = f2bf(v);
}

__global__ __launch_bounds__(256) void cvt_wo_k(
    const float* __restrict__ ow, u16* __restrict__ wt)
{
    const int idx = blockIdx.x * 256 + threadIdx.x;   // idx = n*768 + k
    if (idx >= DM * DM) return;
    const int k = idx % DM;
    const int n = idx / DM;
    wt[idx] = f2bf(ow[(size_t)k * DM + n]);
}

// ======== 128x128-tile bf16 MFMA GEMM body: ring-4 counted-vmcnt pipeline ===
// STAGE(kt+2) -> s_waitcnt vmcnt(8) (keeps batches kt+1,kt+2 in flight; drains
// batch kt) -> s_barrier -> compute slot kt&3.  ONE barrier/iter; WAR safety:
// slot (kt+2)&3 was last read at compute(kt-2), finished before barrier kt-1
// by every wave (we only issue STAGE after passing that barrier).
__device__ __forceinline__ void gemm128_body(
    const u16* __restrict__ A, const u16* __restrict__ B,
    int m0, int n0, u16 (*As)[4096], u16 (*Bs)[4096], f32x4 acc[4][4])
{
    const int tid  = threadIdx.x;
    const int lane = tid & 63;
    const int wid  = tid >> 6;
    const int wr = wid >> 1, wc = wid & 1;
    const int lo = lane & 15, hi = lane >> 4;

    const f32x4 z = {0.f, 0.f, 0.f, 0.f};
    #pragma unroll
    for (int i = 0; i < 4; i++)
        #pragma unroll
        for (int j = 0; j < 4; j++)
            acc[i][j] = z;

    const int NT = DM / 32;                   // 24 K-steps

    #define STAGE_G(kt_, sl_) do {                                            \
        _Pragma("unroll")                                                     \
        for (int r_ = 0; r_ < 2; ++r_) {                                      \
            const int idx_  = r_ * 256 + tid;                                 \
            const int row_  = idx_ >> 2;                                      \
            const int col_  = (idx_ & 3) << 3;                                \
            const int base_ = (r_ * 256 + wid * 64) * 8;                      \
            __builtin_amdgcn_global_load_lds(                                 \
                (gu32_c*)&A[(size_t)(m0 + row_) * DM + (kt_) * 32 + col_],    \
                (su32*)&As[sl_][base_], 16, 0, 0);                            \
            __builtin_amdgcn_global_load_lds(                                 \
                (gu32_c*)&B[(size_t)(n0 + row_) * DM + (kt_) * 32 + col_],    \
                (su32*)&Bs[sl_][base_], 16, 0, 0);                            \
        }                                                                     \
    } while (0)

    STAGE_G(0, 0);
    STAGE_G(1, 1);

    for (int kt = 0; kt < NT; ++kt) {
        const int k2 = (kt + 2 < NT) ? kt + 2 : NT - 1;   // clamp: extra stages never read
        STAGE_G(k2, (kt + 2) & 3);
        asm volatile("s_waitcnt vmcnt(8)" ::: "memory");
        __builtin_amdgcn_s_barrier();
        __builtin_amdgcn_sched_barrier(0);

        const int sl = kt & 3;
        bf16x8 af[4], bfr[4];
        #pragma unroll
        for (int i = 0; i < 4; i++) af[i]  = *(const bf16x8*)&As[sl][(wr * 64 + i * 16 + lo) * 32 + hi * 8];
        #pragma unroll
        for (int j = 0; j < 4; j++) bfr[j] = *(const bf16x8*)&Bs[sl][(wc * 64 + j * 16 + lo) * 32 + hi * 8];
        #pragma unroll
        for (int i = 0; i < 4; i++)
            #pragma unroll
            for (int j = 0; j < 4; j++)
                acc[i][j] = __builtin_amdgcn_mfma_f32_16x16x32_bf16(af[i], bfr[j], acc[i][j], 0, 0, 0);
    }
    #undef STAGE_G
}

// ======== QKV projection -> Q/K/V ALL head-major [b,H,t,d] coalesced ========
__global__ __launch_bounds__(256) void gemm_qkv(
    const u16* __restrict__ xb, const u16* __restrict__ wt,
    const float* __restrict__ qb, const float* __restrict__ kb,
    const float* __restrict__ vb,
    u16* __restrict__ Q, u16* __restrict__ K, u16* __restrict__ Vr)
{
    __shared__ __align__(16) u16 As[4][4096];
    __shared__ __align__(16) u16 Bs[4][4096];
    const int id = (blockIdx.x & 7) * 80 + (blockIdx.x >> 3);
    const int m0 = (id / 10) * 128;
    const int n0 = (id % 10) * 128;
    f32x4 acc[4][4];
    gemm128_body(xb, wt, m0, n0, As, Bs, acc);

    const int tid = threadIdx.x;
    const int lane = tid & 63, wid = tid >> 6;
    const int wr = wid >> 1, wc = wid & 1;
    const int lo = lane & 15, hi = lane >> 4;

    #pragma unroll
    for (int j = 0; j < 4; j++) {
        const int n = n0 + wc * 64 + j * 16 + lo;
        u16* outp; int nl, Hcnt; float bias;
        if (n < 768)       { outp = Q;  nl = n;        Hcnt = NHEAD; bias = qb[n] * QSCALE; }
        else if (n < 1024) { outp = K;  nl = n - 768;  Hcnt = KVH;   bias = kb[nl]; }
        else               { outp = Vr; nl = n - 1024; Hcnt = KVH;   bias = vb[nl]; }
        const int head = nl >> 6, d = nl & 63;
        #pragma unroll
        for (int i = 0; i < 4; i++) {
            #pragma unroll
            for (int r = 0; r < 4; r++) {
                const int m = m0 + wr * 64 + i * 16 + hi * 4 + r;
                const int b = m >> 10, t = m & 1023;
                outp[(((size_t)(b * Hcnt + head)) * SEQ + t) * HD + d] =
                    f2bf(acc[i][j][r] + bias);
            }
        }
    }
}

// ======== V transpose: [b,g,t,d] -> [b,g,d,t] via LDS bounce ================
__global__ __launch_bounds__(256) void vtrans_k(
    const u16* __restrict__ in, u16* __restrict__ out)
{
    __shared__ u16 T[64][72];
    const int blk = blockIdx.x;               // 32 (b,g) x 16 t-tiles = 512
    const int bg  = blk >> 4;
    const int t0  = (blk & 15) << 6;
    const int tid = threadIdx.x;
    const int tl  = tid & 63;
    const int d0  = (tid >> 6) << 4;          // 0,16,32,48

    union { u32x4 v[2]; u16 u[16]; } ld;
    const u16* src = in + ((size_t)bg * SEQ + t0 + tl) * HD + d0;
    ld.v[0] = *(const u32x4*)(src);
    ld.v[1] = *(const u32x4*)(src + 8);
    #pragma unroll
    for (int k = 0; k < 16; ++k) T[d0 + k][tl] = ld.u[k];
    __syncthreads();

    const int d  = tid >> 2;
    const int tc = (tid & 3) << 4;
    u16* dst = out + ((size_t)bg * HD + d) * SEQ + t0 + tc;
    *(u32x4*)(dst)     = *(const u32x4*)&T[d][tc];
    *(u32x4*)(dst + 8) = *(const u32x4*)&T[d][tc + 8];
}

// ======== output projection: attn[8192][768] bf16 @ Wo^T + ob -> fp32 =======
__global__ __launch_bounds__(256) void gemm_oproj(
    const u16* __restrict__ Ab, const u16* __restrict__ wt,
    const float* __restrict__ ob, float* __restrict__ outp)
{
    __shared__ __align__(16) u16 As[4][4096];
    __shared__ __align__(16) u16 Bs[4][4096];
    const int id = (blockIdx.x & 7) * 48 + (blockIdx.x >> 3);   // 384 % 8 == 0
    const int m0 = (id / 6) * 128;
    const int n0 = (id % 6) * 128;
    f32x4 acc[4][4];
    gemm128_body(Ab, wt, m0, n0, As, Bs, acc);

    const int tid = threadIdx.x;
    const int lane = tid & 63, wid = tid >> 6;
    const int wr = wid >> 1, wc = wid & 1;
    const int lo = lane & 15, hi = lane >> 4;

    #pragma unroll
    for (int j = 0; j < 4; j++) {
        const int n = n0 + wc * 64 + j * 16 + lo;
        const float bias = ob[n];
        #pragma unroll
        for (int i = 0; i < 4; i++) {
            #pragma unroll
            for (int r = 0; r < 4; r++) {
                const int m = m0 + wr * 64 + i * 16 + hi * 4 + r;
                outp[(size_t)m * DM + n] = acc[i][j][r] + bias;
            }
        }
    }
}

// ======== RoPE, Q and K fused in one launch (file-faithful interleave) ======
__global__ __launch_bounds__(256) void rope_naive(
    const __hip_bfloat16* __restrict__ Qin, __hip_bfloat16* __restrict__ Qout,
    const __hip_bfloat16* __restrict__ Kin, __hip_bfloat16* __restrict__ Kout,
    const int* __restrict__ pos)
{
    const long long qrows = (long long)BATCH * NHEAD * SEQ;   // 98304
    const long long krows = (long long)BATCH * KVH * SEQ;     // 32768
    const long long gid = (long long)blockIdx.x * 256 + threadIdx.x;
    if (gid >= (qrows + krows) * 64) return;
    long long row = gid >> 6;
    const int j = (int)(gid & 63);
    const __hip_bfloat16* in; __hip_bfloat16* outb;
    if (row < qrows) { in = Qin; outb = Qout; }
    else             { in = Kin; outb = Kout; row -= qrows; }
    const int t = (int)(row & (SEQ - 1));

    float p;
    if (pos[1] == 1)                              p = (float)pos[t];
    else if (((const float*)pos)[1] == 1.0f)      p = ((const float*)pos)[t];
    else                                          p = (float)pos[2 * t];

    const float inv = exp2f(-(float)(j & 31) * (13.287712379549449f / 32.0f));
    float sv, cv;
    sincosf(p * inv, &sv, &cv);
    const int partner = (j & 1) * 32 + (j >> 1) + ((j < 32) ? 16 : -16);
    const float sign  = (j < 32) ? -1.0f : 1.0f;
    const float val  = __bfloat162float(in[row * HD + j]);
    const float pv   = __bfloat162float(in[row * HD + partner]);
    outb[row * HD + j] = __float2bfloat16(val * cv + sign * pv * sv);
}

// ======== flash attention v8: v6 strip-pairs + ring-4 counted-vmcnt =========
// Block = (b,h) x 8; 4 waves.  Wave w = c + 8*wid owns strips (63-w, w):
// uniform ~33 active tiles/wave (v7's single-strip split idled waves -> -27%).
// Ring-4 LDS (32KB), prefetch 2 tiles ahead, s_waitcnt vmcnt(10) (batches
// st+1,st+2 = 10 ops stay in flight), ONE raw s_barrier per iteration.
__device__ __forceinline__ void strip_compute(
    const bf16x8& qf0, const bf16x8& qf1,
    const bf16x8& k0, const bf16x8& k1, const bf16x8& k2, const bf16x8& k3,
    const bf16x8* vv, bool diag, int msk0, int hi,
    float& m, float& l, f32x4* O)
{
    const f32x4 z = {0.f, 0.f, 0.f, 0.f};
    f32x4 a0 = z, a1 = z;
    __builtin_amdgcn_s_setprio(1);
    a0 = __builtin_amdgcn_mfma_f32_16x16x32_bf16(k0, qf0, a0, 0, 0, 0);
    a0 = __builtin_amdgcn_mfma_f32_16x16x32_bf16(k1, qf1, a0, 0, 0, 0);
    a1 = __builtin_amdgcn_mfma_f32_16x16x32_bf16(k2, qf0, a1, 0, 0, 0);
    a1 = __builtin_amdgcn_mfma_f32_16x16x32_bf16(k3, qf1, a1, 0, 0, 0);
    __builtin_amdgcn_s_setprio(0);

    float sc[8];
    #pragma unroll
    for (int e = 0; e < 8; ++e)
        sc[e] = (e < 4) ? a0[e & 3] : a1[e & 3];
    if (diag) {
        #pragma unroll
        for (int e = 0; e < 8; ++e) {
            const int srel = ((e >> 2) << 4) + (hi << 2) + (e & 3);
            if (srel > msk0) sc[e] = -3.0e38f;
        }
    }
    float pm = sc[0];
    #pragma unroll
    for (int e = 1; e < 8; ++e) pm = fmaxf(pm, sc[e]);

    if (!__all(pm - m <= 8.0f)) {            // defer-max (per-lane == per-row)
        float pr = fmaxf(pm, __shfl_xor(pm, 16));
        pr = fmaxf(pr, __shfl_xor(pr, 32));
        const float mn = fmaxf(m, pr);
        const float f = exp2f(m - mn);       // first tile: m=-3e38 -> f=0
        l *= f;
        #pragma unroll
        for (int r = 0; r < 4; ++r) {
            const float fr = __shfl(f, hi * 4 + r);
            #pragma unroll
            for (int dj = 0; dj < 4; ++dj) O[dj][r] *= fr;
        }
        m = mn;
    }

    union { u16 u[8]; bf16x8 v; } pu;
    float ps = 0.f;
    #pragma unroll
    for (int e = 0; e < 8; ++e) {
        const float p = exp2f(sc[e] - m);    // bounded by 2^8
        ps += p;
        pu.u[e] = f2bf(p);
    }
    l += ps;                                  // per-lane partial

    __builtin_amdgcn_s_setprio(1);
    #pragma unroll
    for (int dj = 0; dj < 4; ++dj)
        O[dj] = __builtin_amdgcn_mfma_f32_16x16x32_bf16(pu.v, vv[dj], O[dj], 0, 0, 0);
    __builtin_amdgcn_s_setprio(0);
}

__global__ __launch_bounds__(256, 2) void attn_mfma(
    const u16* __restrict__ Q, const u16* __restrict__ K,
    const u16* __restrict__ Vt, u16* __restrict__ outp)
{
    __shared__ __align__(16) u16 Ks[4][2048];   // ring-4: 32 s x 64 d, swizzled
    __shared__ __align__(16) u16 Vs[4][2048];   // ring-4: 64 d x 32 s, permuted

    const int wg = (blockIdx.x & 7) * 96 + (blockIdx.x >> 3);   // XCD swizzle
    const int bh = wg >> 3;
    const int c  = wg & 7;
    const int b  = bh / NHEAD, h = bh % NHEAD;
    const int g  = h / REP;
    const int wid  = threadIdx.x >> 6;
    const int lane = threadIdx.x & 63;
    const int lo = lane & 15, hi = lane >> 4;

    const int w    = c + (wid << 3);             // 0..31
    const int sA   = 63 - w, sB = w;             // strip pair (16 rows each)
    const int dA   = sA >> 1, dB = sB >> 1;      // diagonal tile indices
    const int mskA = lo + ((sA & 1) << 4);
    const int mskB = lo + ((sB & 1) << 4);
    const int nstT = ((63 - c) >> 1) + 1;        // block-uniform trip count (29..32)

    const u16* Kp = K  + (size_t)(b * KVH + g) * SEQ * HD;
    const u16* Vp = Vt + (size_t)(b * KVH + g) * SEQ * HD;   // [d][s]

    // K: 16B units j; dest linear j = wid*64+lane; src unit = j ^ ((j>>3)&7)
    const int jK = (wid << 6) + lane;
    const int sKoff = (jK ^ ((jK >> 3) & 7)) << 3;           // u16 offset
    // V: 4B dwords; dest dw = wid*256 + q*64 + lane (r8 permutation, 0 conflicts)
    int vsoff[4];
    #pragma unroll
    for (int q = 0; q < 4; ++q) {
        const int dw  = (wid << 8) + (q << 6) + lane;
        const int R   = dw >> 4;
        const int wd  = dw & 15;
        const int hpl = (wd >> 2) ^ ((R >> 1) & 3);
        vsoff[q] = (R << 10) + (hpl << 2) + (((wd >> 1) & 1) << 4) + ((wd & 1) << 1);
    }

    // Q fragments for both strips
    const u16* QpA = Q + ((size_t)(b * NHEAD + h) * SEQ + (sA << 4)) * HD;
    const u16* QpB = Q + ((size_t)(b * NHEAD + h) * SEQ + (sB << 4)) * HD;
    const bf16x8 qA0 = *(const bf16x8*)&QpA[(size_t)lo * HD + hi * 8];
    const bf16x8 qA1 = *(const bf16x8*)&QpA[(size_t)lo * HD + 32 + hi * 8];
    const bf16x8 qB0 = *(const bf16x8*)&QpB[(size_t)lo * HD + hi * 8];
    const bf16x8 qB1 = *(const bf16x8*)&QpB[(size_t)lo * HD + 32 + hi * 8];

    const f32x4 z = {0.f, 0.f, 0.f, 0.f};
    f32x4 OA[4], OB[4];
    #pragma unroll
    for (int dj = 0; dj < 4; ++dj) { OA[dj] = z; OB[dj] = z; }
    float mA = -3.0e38f, lA = 0.f, mB = -3.0e38f, lB = 0.f;

    #define STAGE(st_, sl_) do {                                              \
        const int s0_ = (st_) << 5;                                           \
        __builtin_amdgcn_global_load_lds(                                     \
            (gu32_c*)(Kp + (s0_ << 6) + sKoff),                               \
            (su32*)&Ks[sl_][wid << 9], 16, 0, 0);                             \
        _Pragma("unroll")                                                     \
        for (int q_ = 0; q_ < 4; ++q_)                                        \
            __builtin_amdgcn_global_load_lds(                                 \
                (gu32_c*)(Vp + s0_ + vsoff[q_]),                              \
                (su32*)&Vs[sl_][(wid << 9) + (q_ << 7)], 4, 0, 0);            \
    } while (0)

    STAGE(0, 0);
    STAGE(1, 1);

    const int xorK = lo & 7;
    for (int st = 0; st < nstT; ++st) {
        const int s2 = (st + 2 < nstT) ? st + 2 : nstT - 1;  // clamp: never read
        STAGE(s2, (st + 2) & 3);
        asm volatile("s_waitcnt vmcnt(10)" ::: "memory");
        __builtin_amdgcn_s_barrier();
        __builtin_amdgcn_sched_barrier(0);

        if (st <= dA) {
            const int sl = st & 3;
            const u16* kb_ = Ks[sl];
            const bf16x8 k0 = *(const bf16x8*)&kb_[((lo << 3) + (hi ^ xorK)) << 3];
            const bf16x8 k1 = *(const bf16x8*)&kb_[((lo << 3) + ((4 + hi) ^ xorK)) << 3];
            const bf16x8 k2 = *(const bf16x8*)&kb_[(((16 + lo) << 3) + (hi ^ xorK)) << 3];
            const bf16x8 k3 = *(const bf16x8*)&kb_[(((16 + lo) << 3) + ((4 + hi) ^ xorK)) << 3];
            bf16x8 vv[4];
            #pragma unroll
            for (int dj = 0; dj < 4; ++dj) {
                const int R = dj * 16 + lo;
                vv[dj] = *(const bf16x8*)&Vs[sl][(R << 5) + ((hi ^ ((R >> 1) & 3)) << 3)];
            }
            strip_compute(qA0, qA1, k0, k1, k2, k3, vv, st == dA, mskA, hi, mA, lA, OA);
            if (st <= dB)
                strip_compute(qB0, qB1, k0, k1, k2, k3, vv, st == dB, mskB, hi, mB, lB, OB);
        }
    }
    #undef STAGE

    // epilogue: reduce per-lane l across hi-groups, then per-row store
    lA += __shfl_xor(lA, 16); lA += __shfl_xor(lA, 32);
    lB += __shfl_xor(lB, 16); lB += __shfl_xor(lB, 32);
    #pragma unroll
    for (int r = 0; r < 4; ++r) {
        const float liA = 1.0f / fmaxf(__shfl(lA, hi * 4 + r), 1e-37f);
        const float liB = 1.0f / fmaxf(__shfl(lB, hi * 4 + r), 1e-37f);
        const int tA = (sA << 4) + hi * 4 + r;
        const int tB = (sB << 4) + hi * 4 + r;
        #pragma unroll
        for (int dj = 0; dj < 4; ++dj) {
            outp[((size_t)(b * SEQ + tA)) * DM + h * HD + dj * 16 + lo] = f2bf(OA[dj][r] * liA);
            outp[((size_t)(b * SEQ + tB)) * DM + h * HD + dj * 16 + lo] = f2bf(OB[dj][r] * liB);
        }
    }
}

extern "C" void kernel_launch(void* const* d_in, const int* in_sizes, int n_in,
                              void* d_out, int out_size, void* d_ws, size_t ws_size,
                              hipStream_t stream) {
    const float* x   = (const float*)d_in[0];
    const int*   pos = (const int*)d_in[1];
    const float* qw  = (const float*)d_in[2];
    const float* qb  = (const float*)d_in[3];
    const float* kw  = (const float*)d_in[4];
    const float* kb  = (const float*)d_in[5];
    const float* vw  = (const float*)d_in[6];
    const float* vb  = (const float*)d_in[7];
    const float* ow  = (const float*)d_in[8];
    const float* ob  = (const float*)d_in[9];
    float* out = (float*)d_out;                 // OUTPUT IS FP32

    u16* xb    = (u16*)d_ws;                                    // 6291456
    u16* Wqkvt = xb    + (size_t)8192 * DM;                     //  983040
    u16* Wot   = Wqkvt + (size_t)1280 * DM;                     //  589824
    u16* Qbuf  = Wot   + (size_t)DM * DM;                       // 6291456
    u16* Kbuf  = Qbuf  + (size_t)BATCH * NHEAD * SEQ * HD;      // 2097152
    u16* Krot  = Kbuf  + (size_t)BATCH * KVH * SEQ * HD;        // 2097152
    u16* Vtb   = Krot  + (size_t)BATCH * KVH * SEQ * HD;        // 2097152 [b,g,d,s]
    u16* Qrot  = xb;     // alias: xb dead after gemm_qkv
    u16* attn  = Qbuf;   // alias: Qbuf dead after rope
    u16* Vraw  = Krot;   // alias: [b,g,t,d], dead after vtrans (before rope writes Krot)

    cvt_x_k<<<(8192 * DM / 4 + 255) / 256, 256, 0, stream>>>(x, xb, 8192 * DM / 4);
    cvt_wqkv_k<<<(1280 * DM + 255) / 256, 256, 0, stream>>>(qw, kw, vw, Wqkvt);
    cvt_wo_k<<<(DM * DM + 255) / 256, 256, 0, stream>>>(ow, Wot);

    gemm_qkv<<<640, 256, 0, stream>>>(xb, Wqkvt, qb, kb, vb, Qbuf, Kbuf, Vraw);

    vtrans_k<<<512, 256, 0, stream>>>(Vraw, Vtb);   // before rope overwrites Krot

    const long long allrows = (long long)BATCH * (NHEAD + KVH) * SEQ;  // 131072
    rope_naive<<<(int)((allrows * 64 + 255) / 256), 256, 0, stream>>>(
        (const __hip_bfloat16*)Qbuf, (__hip_bfloat16*)Qrot,
        (const __hip_bfloat16*)Kbuf, (__hip_bfloat16*)Krot, pos);

    attn_mfma<<<96 * 8, 256, 0, stream>>>(Qrot, Krot, Vtb, attn);

    gemm_oproj<<<384, 256, 0, stream>>>(attn, Wot, ob, out);
}

// Round 10
// 215.106 us; speedup vs baseline: 1.5742x; 1.0683x over previous
//
#include <hip/hip_runtime.h>
#include <hip/hip_bf16.h>
#include <math.h>

#define BATCH 8
#define SEQ   1024
#define DM    768
#define NHEAD 12
#define KVH   4
#define HD    64
#define REP   3

// softmax scale folded into Q weights, exp2 domain: 0.125 * log2(e)
#define QSCALE 0.18033688011112042f

typedef unsigned short u16;
typedef __attribute__((ext_vector_type(8))) __bf16 bf16x8;
typedef __attribute__((ext_vector_type(4))) float f32x4;
typedef __attribute__((ext_vector_type(4))) unsigned int u32x4;
typedef __attribute__((address_space(1))) const unsigned int gu32_c;
typedef __attribute__((address_space(3))) unsigned int su32;

// RTNE fp32 -> bf16 (finite values)
__device__ __forceinline__ u16 f2bf(float f) {
    unsigned int u = __float_as_uint(f);
    u += 0x7fffu + ((u >> 16) & 1u);
    return (u16)(u >> 16);
}

// ======== fused converts: x->bf16, Wqkv^T (Q cols pre-scaled), Wo^T ==========
__global__ __launch_bounds__(256) void cvt_all(
    const float* __restrict__ x,
    const float* __restrict__ qw, const float* __restrict__ kw,
    const float* __restrict__ vw, const float* __restrict__ ow,
    u16* __restrict__ xb, u16* __restrict__ wqkvt, u16* __restrict__ wot)
{
    const int NX = 8192 * DM / 4;          // float4 items
    const int NW = 1280 * DM;
    const int NO = DM * DM;
    const int i = blockIdx.x * 256 + threadIdx.x;
    if (i < NX) {
        const float4 v = ((const float4*)x)[i];
        ushort4 r;
        r.x = f2bf(v.x); r.y = f2bf(v.y); r.z = f2bf(v.z); r.w = f2bf(v.w);
        ((ushort4*)xb)[i] = r;
    } else if (i < NX + NW) {
        const int idx = i - NX;                // idx = n*768 + k
        const int k = idx % DM;
        const int n = idx / DM;
        float v;
        if (n < 768)       v = qw[(size_t)k * 768 + n] * QSCALE;
        else if (n < 1024) v = kw[(size_t)k * 256 + (n - 768)];
        else               v = vw[(size_t)k * 256 + (n - 1024)];
        wqkvt[idx] = f2bf(v);
    } else if (i < NX + NW + NO) {
        const int idx = i - NX - NW;
        const int k = idx % DM;
        const int n = idx / DM;
        wot[idx] = f2bf(ow[(size_t)k * DM + n]);
    }
}

// ======== 128x128-tile bf16 MFMA GEMM body: ring-4 counted-vmcnt pipeline ===
// STAGE(kt+2) -> s_waitcnt vmcnt(8) (keeps batches kt+1,kt+2 in flight; drains
// batch kt) -> s_barrier -> compute slot kt&3.  ONE barrier/iter; WAR safety:
// slot (kt+2)&3 was last read at compute(kt-2), finished before barrier kt-1
// by every wave (we only issue STAGE after passing that barrier).
__device__ __forceinline__ void gemm128_body(
    const u16* __restrict__ A, const u16* __restrict__ B,
    int m0, int n0, u16 (*As)[4096], u16 (*Bs)[4096], f32x4 acc[4][4])
{
    const int tid  = threadIdx.x;
    const int lane = tid & 63;
    const int wid  = tid >> 6;
    const int wr = wid >> 1, wc = wid & 1;
    const int lo = lane & 15, hi = lane >> 4;

    const f32x4 z = {0.f, 0.f, 0.f, 0.f};
    #pragma unroll
    for (int i = 0; i < 4; i++)
        #pragma unroll
        for (int j = 0; j < 4; j++)
            acc[i][j] = z;

    const int NT = DM / 32;                   // 24 K-steps

    #define STAGE_G(kt_, sl_) do {                                            \
        _Pragma("unroll")                                                     \
        for (int r_ = 0; r_ < 2; ++r_) {                                      \
            const int idx_  = r_ * 256 + tid;                                 \
            const int row_  = idx_ >> 2;                                      \
            const int col_  = (idx_ & 3) << 3;                                \
            const int base_ = (r_ * 256 + wid * 64) * 8;                      \
            __builtin_amdgcn_global_load_lds(                                 \
                (gu32_c*)&A[(size_t)(m0 + row_) * DM + (kt_) * 32 + col_],    \
                (su32*)&As[sl_][base_], 16, 0, 0);                            \
            __builtin_amdgcn_global_load_lds(                                 \
                (gu32_c*)&B[(size_t)(n0 + row_) * DM + (kt_) * 32 + col_],    \
                (su32*)&Bs[sl_][base_], 16, 0, 0);                            \
        }                                                                     \
    } while (0)

    STAGE_G(0, 0);
    STAGE_G(1, 1);

    for (int kt = 0; kt < NT; ++kt) {
        const int k2 = (kt + 2 < NT) ? kt + 2 : NT - 1;   // clamp: extra stages never read
        STAGE_G(k2, (kt + 2) & 3);
        asm volatile("s_waitcnt vmcnt(8)" ::: "memory");
        __builtin_amdgcn_s_barrier();
        __builtin_amdgcn_sched_barrier(0);

        const int sl = kt & 3;
        bf16x8 af[4], bfr[4];
        #pragma unroll
        for (int i = 0; i < 4; i++) af[i]  = *(const bf16x8*)&As[sl][(wr * 64 + i * 16 + lo) * 32 + hi * 8];
        #pragma unroll
        for (int j = 0; j < 4; j++) bfr[j] = *(const bf16x8*)&Bs[sl][(wc * 64 + j * 16 + lo) * 32 + hi * 8];
        #pragma unroll
        for (int i = 0; i < 4; i++)
            #pragma unroll
            for (int j = 0; j < 4; j++)
                acc[i][j] = __builtin_amdgcn_mfma_f32_16x16x32_bf16(af[i], bfr[j], acc[i][j], 0, 0, 0);
    }
    #undef STAGE_G
}

// ======== QKV projection -> Q/K/V ALL head-major [b,H,t,d] coalesced ========
__global__ __launch_bounds__(256) void gemm_qkv(
    const u16* __restrict__ xb, const u16* __restrict__ wt,
    const float* __restrict__ qb, const float* __restrict__ kb,
    const float* __restrict__ vb,
    u16* __restrict__ Q, u16* __restrict__ K, u16* __restrict__ Vr)
{
    __shared__ __align__(16) u16 As[4][4096];
    __shared__ __align__(16) u16 Bs[4][4096];
    const int id = (blockIdx.x & 7) * 80 + (blockIdx.x >> 3);
    const int m0 = (id / 10) * 128;
    const int n0 = (id % 10) * 128;
    f32x4 acc[4][4];
    gemm128_body(xb, wt, m0, n0, As, Bs, acc);

    const int tid = threadIdx.x;
    const int lane = tid & 63, wid = tid >> 6;
    const int wr = wid >> 1, wc = wid & 1;
    const int lo = lane & 15, hi = lane >> 4;

    #pragma unroll
    for (int j = 0; j < 4; j++) {
        const int n = n0 + wc * 64 + j * 16 + lo;
        u16* outp; int nl, Hcnt; float bias;
        if (n < 768)       { outp = Q;  nl = n;        Hcnt = NHEAD; bias = qb[n] * QSCALE; }
        else if (n < 1024) { outp = K;  nl = n - 768;  Hcnt = KVH;   bias = kb[nl]; }
        else               { outp = Vr; nl = n - 1024; Hcnt = KVH;   bias = vb[nl]; }
        const int head = nl >> 6, d = nl & 63;
        #pragma unroll
        for (int i = 0; i < 4; i++) {
            #pragma unroll
            for (int r = 0; r < 4; r++) {
                const int m = m0 + wr * 64 + i * 16 + hi * 4 + r;
                const int b = m >> 10, t = m & 1023;
                outp[(((size_t)(b * Hcnt + head)) * SEQ + t) * HD + d] =
                    f2bf(acc[i][j][r] + bias);
            }
        }
    }
}

// ======== V transpose: [b,g,t,d] -> [b,g,d,t] via LDS bounce ================
__global__ __launch_bounds__(256) void vtrans_k(
    const u16* __restrict__ in, u16* __restrict__ out)
{
    __shared__ u16 T[64][72];
    const int blk = blockIdx.x;               // 32 (b,g) x 16 t-tiles = 512
    const int bg  = blk >> 4;
    const int t0  = (blk & 15) << 6;
    const int tid = threadIdx.x;
    const int tl  = tid & 63;
    const int d0  = (tid >> 6) << 4;          // 0,16,32,48

    union { u32x4 v[2]; u16 u[16]; } ld;
    const u16* src = in + ((size_t)bg * SEQ + t0 + tl) * HD + d0;
    ld.v[0] = *(const u32x4*)(src);
    ld.v[1] = *(const u32x4*)(src + 8);
    #pragma unroll
    for (int k = 0; k < 16; ++k) T[d0 + k][tl] = ld.u[k];
    __syncthreads();

    const int d  = tid >> 2;
    const int tc = (tid & 3) << 4;
    u16* dst = out + ((size_t)bg * HD + d) * SEQ + t0 + tc;
    *(u32x4*)(dst)     = *(const u32x4*)&T[d][tc];
    *(u32x4*)(dst + 8) = *(const u32x4*)&T[d][tc + 8];
}

// ======== output projection: attn[8192][768] bf16 @ Wo^T + ob -> fp32 =======
__global__ __launch_bounds__(256) void gemm_oproj(
    const u16* __restrict__ Ab, const u16* __restrict__ wt,
    const float* __restrict__ ob, float* __restrict__ outp)
{
    __shared__ __align__(16) u16 As[4][4096];
    __shared__ __align__(16) u16 Bs[4][4096];
    const int id = (blockIdx.x & 7) * 48 + (blockIdx.x >> 3);   // 384 % 8 == 0
    const int m0 = (id / 6) * 128;
    const int n0 = (id % 6) * 128;
    f32x4 acc[4][4];
    gemm128_body(Ab, wt, m0, n0, As, Bs, acc);

    const int tid = threadIdx.x;
    const int lane = tid & 63, wid = tid >> 6;
    const int wr = wid >> 1, wc = wid & 1;
    const int lo = lane & 15, hi = lane >> 4;

    #pragma unroll
    for (int j = 0; j < 4; j++) {
        const int n = n0 + wc * 64 + j * 16 + lo;
        const float bias = ob[n];
        #pragma unroll
        for (int i = 0; i < 4; i++) {
            #pragma unroll
            for (int r = 0; r < 4; r++) {
                const int m = m0 + wr * 64 + i * 16 + hi * 4 + r;
                outp[(size_t)m * DM + n] = acc[i][j][r] + bias;
            }
        }
    }
}

// ======== RoPE, Q and K fused in one launch (file-faithful interleave) ======
__global__ __launch_bounds__(256) void rope_naive(
    const __hip_bfloat16* __restrict__ Qin, __hip_bfloat16* __restrict__ Qout,
    const __hip_bfloat16* __restrict__ Kin, __hip_bfloat16* __restrict__ Kout,
    const int* __restrict__ pos)
{
    const long long qrows = (long long)BATCH * NHEAD * SEQ;   // 98304
    const long long krows = (long long)BATCH * KVH * SEQ;     // 32768
    const long long gid = (long long)blockIdx.x * 256 + threadIdx.x;
    if (gid >= (qrows + krows) * 64) return;
    long long row = gid >> 6;
    const int j = (int)(gid & 63);
    const __hip_bfloat16* in; __hip_bfloat16* outb;
    if (row < qrows) { in = Qin; outb = Qout; }
    else             { in = Kin; outb = Kout; row -= qrows; }
    const int t = (int)(row & (SEQ - 1));

    float p;
    if (pos[1] == 1)                              p = (float)pos[t];
    else if (((const float*)pos)[1] == 1.0f)      p = ((const float*)pos)[t];
    else                                          p = (float)pos[2 * t];

    const float inv = exp2f(-(float)(j & 31) * (13.287712379549449f / 32.0f));
    float sv, cv;
    sincosf(p * inv, &sv, &cv);
    const int partner = (j & 1) * 32 + (j >> 1) + ((j < 32) ? 16 : -16);
    const float sign  = (j < 32) ? -1.0f : 1.0f;
    const float val  = __bfloat162float(in[row * HD + j]);
    const float pv   = __bfloat162float(in[row * HD + partner]);
    outb[row * HD + j] = __float2bfloat16(val * cv + sign * pv * sv);
}

// ======== flash attention v9: row-split waves, LPT-ordered q-blocks =========
// Block = (b, h, q-block a) of 64 q-rows; 4 waves each own 16 rows (strip
// w = 4a+wid).  All waves need the SAME tile range -> wave spans differ by
// <=1 round: slot utilization ~97% (v8 strip-pairs: 67%, waves idled at
// barriers when only one strip was live).  Trip count 2a+2 varies per block:
// grid is LPT-ordered (big a first per XCD) and (b,g) KV groups are pinned
// per-XCD for L2 locality.  Staging ring-4 + counted vmcnt as r9.
__device__ __forceinline__ void strip_compute(
    const bf16x8& qf0, const bf16x8& qf1,
    const bf16x8& k0, const bf16x8& k1, const bf16x8& k2, const bf16x8& k3,
    const bf16x8* vv, bool diag, int msk0, int hi,
    float& m, float& l, f32x4* O)
{
    const f32x4 z = {0.f, 0.f, 0.f, 0.f};
    f32x4 a0 = z, a1 = z;
    __builtin_amdgcn_s_setprio(1);
    a0 = __builtin_amdgcn_mfma_f32_16x16x32_bf16(k0, qf0, a0, 0, 0, 0);
    a0 = __builtin_amdgcn_mfma_f32_16x16x32_bf16(k1, qf1, a0, 0, 0, 0);
    a1 = __builtin_amdgcn_mfma_f32_16x16x32_bf16(k2, qf0, a1, 0, 0, 0);
    a1 = __builtin_amdgcn_mfma_f32_16x16x32_bf16(k3, qf1, a1, 0, 0, 0);
    __builtin_amdgcn_s_setprio(0);

    float sc[8];
    #pragma unroll
    for (int e = 0; e < 8; ++e)
        sc[e] = (e < 4) ? a0[e & 3] : a1[e & 3];
    if (diag) {
        #pragma unroll
        for (int e = 0; e < 8; ++e) {
            const int srel = ((e >> 2) << 4) + (hi << 2) + (e & 3);
            if (srel > msk0) sc[e] = -3.0e38f;
        }
    }
    float pm = sc[0];
    #pragma unroll
    for (int e = 1; e < 8; ++e) pm = fmaxf(pm, sc[e]);

    if (!__all(pm - m <= 8.0f)) {            // defer-max (per-lane == per-row)
        float pr = fmaxf(pm, __shfl_xor(pm, 16));
        pr = fmaxf(pr, __shfl_xor(pr, 32));
        const float mn = fmaxf(m, pr);
        const float f = exp2f(m - mn);       // first tile: m=-3e38 -> f=0
        l *= f;
        #pragma unroll
        for (int r = 0; r < 4; ++r) {
            const float fr = __shfl(f, hi * 4 + r);
            #pragma unroll
            for (int dj = 0; dj < 4; ++dj) O[dj][r] *= fr;
        }
        m = mn;
    }

    union { u16 u[8]; bf16x8 v; } pu;
    float ps = 0.f;
    #pragma unroll
    for (int e = 0; e < 8; ++e) {
        const float p = exp2f(sc[e] - m);    // bounded by 2^8
        ps += p;
        pu.u[e] = f2bf(p);
    }
    l += ps;                                  // per-lane partial

    __builtin_amdgcn_s_setprio(1);
    #pragma unroll
    for (int dj = 0; dj < 4; ++dj)
        O[dj] = __builtin_amdgcn_mfma_f32_16x16x32_bf16(pu.v, vv[dj], O[dj], 0, 0, 0);
    __builtin_amdgcn_s_setprio(0);
}

__global__ __launch_bounds__(256, 4) void attn_mfma(
    const u16* __restrict__ Q, const u16* __restrict__ K,
    const u16* __restrict__ Vt, u16* __restrict__ outp)
{
    __shared__ __align__(16) u16 Ks[4][2048];   // ring-4: 32 s x 64 d, swizzled
    __shared__ __align__(16) u16 Vs[4][2048];   // ring-4: 64 d x 32 s, permuted

    // LPT + XCD mapping: xcd = blk&7 owns (b,g) groups [4*xcd, 4*xcd+4);
    // within an XCD, blocks arrive a-descending (big trip counts first).
    const int blk = blockIdx.x;                  // 1536 = 8b*12h*16a
    const int xcd = blk & 7;
    const int jj  = blk >> 3;                    // 0..191
    const int bg  = (xcd << 2) + (jj & 3);       // 0..31
    const int rh  = jj >> 2;                     // 0..47
    const int a   = 15 - rh / 3;                 // q-block, DESCENDING
    const int hl  = rh % 3;
    const int b   = bg >> 2, g = bg & 3;
    const int h   = g * REP + hl;

    const int wid  = threadIdx.x >> 6;
    const int lane = threadIdx.x & 63;
    const int lo = lane & 15, hi = lane >> 4;

    const int w    = (a << 2) + wid;             // strip 0..63 (16 q-rows)
    const int q0   = w << 4;
    const int dT   = w >> 1;                     // last tile for this strip
    const int msk0 = lo + ((w & 1) << 4);
    const int nstT = (a << 1) + 2;               // block trip count (= max dT+1)

    const u16* Kp = K  + (size_t)(b * KVH + g) * SEQ * HD;
    const u16* Vp = Vt + (size_t)(b * KVH + g) * SEQ * HD;   // [d][s]

    // K: 16B units j; dest linear j = wid*64+lane; src unit = j ^ ((j>>3)&7)
    const int jK = (wid << 6) + lane;
    const int sKoff = (jK ^ ((jK >> 3) & 7)) << 3;           // u16 offset
    // V: 4B dwords; dest dw = wid*256 + q*64 + lane (r8 permutation, 0 conflicts)
    int vsoff[4];
    #pragma unroll
    for (int q = 0; q < 4; ++q) {
        const int dw  = (wid << 8) + (q << 6) + lane;
        const int R   = dw >> 4;
        const int wd  = dw & 15;
        const int hpl = (wd >> 2) ^ ((R >> 1) & 3);
        vsoff[q] = (R << 10) + (hpl << 2) + (((wd >> 1) & 1) << 4) + ((wd & 1) << 1);
    }

    const u16* Qp = Q + ((size_t)(b * NHEAD + h) * SEQ + q0) * HD;
    const bf16x8 qf0 = *(const bf16x8*)&Qp[(size_t)lo * HD + hi * 8];
    const bf16x8 qf1 = *(const bf16x8*)&Qp[(size_t)lo * HD + 32 + hi * 8];

    const f32x4 z = {0.f, 0.f, 0.f, 0.f};
    f32x4 O[4];
    #pragma unroll
    for (int dj = 0; dj < 4; ++dj) O[dj] = z;
    float m = -3.0e38f, l = 0.f;

    #define STAGE(st_, sl_) do {                                              \
        const int s0_ = (st_) << 5;                                           \
        __builtin_amdgcn_global_load_lds(                                     \
            (gu32_c*)(Kp + (s0_ << 6) + sKoff),                               \
            (su32*)&Ks[sl_][wid << 9], 16, 0, 0);                             \
        _Pragma("unroll")                                                     \
        for (int q_ = 0; q_ < 4; ++q_)                                        \
            __builtin_amdgcn_global_load_lds(                                 \
                (gu32_c*)(Vp + s0_ + vsoff[q_]),                              \
                (su32*)&Vs[sl_][(wid << 9) + (q_ << 7)], 4, 0, 0);            \
    } while (0)

    STAGE(0, 0);
    STAGE(1, 1);

    const int xorK = lo & 7;
    for (int st = 0; st < nstT; ++st) {
        const int s2 = (st + 2 < nstT) ? st + 2 : nstT - 1;  // clamp: never read
        STAGE(s2, (st + 2) & 3);
        asm volatile("s_waitcnt vmcnt(10)" ::: "memory");
        __builtin_amdgcn_s_barrier();
        __builtin_amdgcn_sched_barrier(0);

        if (st <= dT) {
            const int sl = st & 3;
            const u16* kb_ = Ks[sl];
            const bf16x8 k0 = *(const bf16x8*)&kb_[((lo << 3) + (hi ^ xorK)) << 3];
            const bf16x8 k1 = *(const bf16x8*)&kb_[((lo << 3) + ((4 + hi) ^ xorK)) << 3];
            const bf16x8 k2 = *(const bf16x8*)&kb_[(((16 + lo) << 3) + (hi ^ xorK)) << 3];
            const bf16x8 k3 = *(const bf16x8*)&kb_[(((16 + lo) << 3) + ((4 + hi) ^ xorK)) << 3];
            bf16x8 vv[4];
            #pragma unroll
            for (int dj = 0; dj < 4; ++dj) {
                const int R = dj * 16 + lo;
                vv[dj] = *(const bf16x8*)&Vs[sl][(R << 5) + ((hi ^ ((R >> 1) & 3)) << 3)];
            }
            strip_compute(qf0, qf1, k0, k1, k2, k3, vv, st == dT, msk0, hi, m, l, O);
        }
    }
    #undef STAGE

    // epilogue: reduce per-lane l across hi-groups, then per-row store
    l += __shfl_xor(l, 16); l += __shfl_xor(l, 32);
    #pragma unroll
    for (int r = 0; r < 4; ++r) {
        const float li = 1.0f / fmaxf(__shfl(l, hi * 4 + r), 1e-37f);
        const int t = q0 + hi * 4 + r;
        #pragma unroll
        for (int dj = 0; dj < 4; ++dj)
            outp[((size_t)(b * SEQ + t)) * DM + h * HD + dj * 16 + lo] = f2bf(O[dj][r] * li);
    }
}

extern "C" void kernel_launch(void* const* d_in, const int* in_sizes, int n_in,
                              void* d_out, int out_size, void* d_ws, size_t ws_size,
                              hipStream_t stream) {
    const float* x   = (const float*)d_in[0];
    const int*   pos = (const int*)d_in[1];
    const float* qw  = (const float*)d_in[2];
    const float* qb  = (const float*)d_in[3];
    const float* kw  = (const float*)d_in[4];
    const float* kb  = (const float*)d_in[5];
    const float* vw  = (const float*)d_in[6];
    const float* vb  = (const float*)d_in[7];
    const float* ow  = (const float*)d_in[8];
    const float* ob  = (const float*)d_in[9];
    float* out = (float*)d_out;                 // OUTPUT IS FP32

    u16* xb    = (u16*)d_ws;                                    // 6291456
    u16* Wqkvt = xb    + (size_t)8192 * DM;                     //  983040
    u16* Wot   = Wqkvt + (size_t)1280 * DM;                     //  589824
    u16* Qbuf  = Wot   + (size_t)DM * DM;                       // 6291456
    u16* Kbuf  = Qbuf  + (size_t)BATCH * NHEAD * SEQ * HD;      // 2097152
    u16* Krot  = Kbuf  + (size_t)BATCH * KVH * SEQ * HD;        // 2097152
    u16* Vtb   = Krot  + (size_t)BATCH * KVH * SEQ * HD;        // 2097152 [b,g,d,s]
    u16* Qrot  = xb;     // alias: xb dead after gemm_qkv
    u16* attn  = Qbuf;   // alias: Qbuf dead after rope
    u16* Vraw  = Krot;   // alias: [b,g,t,d], dead after vtrans (before rope writes Krot)

    const int NCVT = 8192 * DM / 4 + 1280 * DM + DM * DM;
    cvt_all<<<(NCVT + 255) / 256, 256, 0, stream>>>(x, qw, kw, vw, ow, xb, Wqkvt, Wot);

    gemm_qkv<<<640, 256, 0, stream>>>(xb, Wqkvt, qb, kb, vb, Qbuf, Kbuf, Vraw);

    vtrans_k<<<512, 256, 0, stream>>>(Vraw, Vtb);   // before rope overwrites Krot

    const long long allrows = (long long)BATCH * (NHEAD + KVH) * SEQ;  // 131072
    rope_naive<<<(int)((allrows * 64 + 255) / 256), 256, 0, stream>>>(
        (const __hip_bfloat16*)Qbuf, (__hip_bfloat16*)Qrot,
        (const __hip_bfloat16*)Kbuf, (__hip_bfloat16*)Krot, pos);

    attn_mfma<<<1536, 256, 0, stream>>>(Qrot, Krot, Vtb, attn);

    gemm_oproj<<<384, 256, 0, stream>>>(attn, Wot, ob, out);
}